// Round 1
// baseline (2020.532 us; speedup 1.0000x reference)
//
#include <hip/hip_runtime.h>
#include <hip/hip_bf16.h>

#define E_   512
#define H_   8
#define DH_  64
#define B_   8
#define S_   1024
#define M_   (B_ * S_)      // 8192 rows
#define NTOT (M_ * E_)      // 4,194,304 elements per (B,S,E) buffer

// ---------------------------------------------------------------------------
// Repack per-head weight (H, E, DH) -> (E, H*DH) row-major so all projections
// become a uniform K x N row-major GEMM operand.
__global__ __launch_bounds__(256) void repack_w(const float* __restrict__ in,
                                                float* __restrict__ out) {
    int idx = blockIdx.x * 256 + threadIdx.x;   // over H*E*DH = 262144
    int d = idx & (DH_ - 1);
    int e = (idx >> 6) & (E_ - 1);
    int h = idx >> 15;
    out[e * E_ + h * DH_ + d] = in[idx];
}

// ---------------------------------------------------------------------------
// C[M_ x E_] = A[M_ x E_] @ W[E_ x E_]   (all row-major fp32)
// 64x64 tile, 16x16 threads, 4x4 micro-tile, K-step 16.
__global__ __launch_bounds__(256) void gemm_f32(const float* __restrict__ A,
                                                const float* __restrict__ W,
                                                float* __restrict__ C) {
    __shared__ float As[16][65];   // As[k][m]
    __shared__ float Ws[16][65];   // Ws[k][n]
    int tx = threadIdx.x, ty = threadIdx.y;
    int tid = ty * 16 + tx;
    int bm = blockIdx.y * 64;
    int bn = blockIdx.x * 64;
    float acc[4][4] = {};
    for (int k0 = 0; k0 < E_; k0 += 16) {
        #pragma unroll
        for (int i = 0; i < 4; ++i) {
            int idx = tid + i * 256;            // 1024 elems each
            As[idx & 15][idx >> 4] = A[(bm + (idx >> 4)) * E_ + k0 + (idx & 15)];
            Ws[idx >> 6][idx & 63] = W[(k0 + (idx >> 6)) * E_ + bn + (idx & 63)];
        }
        __syncthreads();
        #pragma unroll
        for (int kk = 0; kk < 16; ++kk) {
            float a[4], b[4];
            #pragma unroll
            for (int i = 0; i < 4; ++i) a[i] = As[kk][ty * 4 + i];
            #pragma unroll
            for (int j = 0; j < 4; ++j) b[j] = Ws[kk][tx * 4 + j];
            #pragma unroll
            for (int i = 0; i < 4; ++i)
                #pragma unroll
                for (int j = 0; j < 4; ++j)
                    acc[i][j] = fmaf(a[i], b[j], acc[i][j]);
        }
        __syncthreads();
    }
    #pragma unroll
    for (int i = 0; i < 4; ++i) {
        float* cp = &C[(size_t)(bm + ty * 4 + i) * E_ + bn + tx * 4];
        #pragma unroll
        for (int j = 0; j < 4; ++j) cp[j] = acc[i][j];
    }
}

// ---------------------------------------------------------------------------
// Parallel multi-scale retention (causal, decay kappa_h^(n-m)).
// Q,K,V,R in (B,S,E) layout with head h occupying columns [h*64, h*64+64).
// One block per (bh, n-tile of 64 rows). m-tiles of 32.
__global__ __launch_bounds__(256) void retention_f32(const float* __restrict__ Q,
                                                     const float* __restrict__ K,
                                                     const float* __restrict__ V,
                                                     float* __restrict__ R) {
    __shared__ float Qs[64][64];   // 16 KB  (reads are broadcast -> no pad)
    __shared__ float Ks[32][65];
    __shared__ float Vs[32][65];
    __shared__ float Ss[64][33];
    int bh = blockIdx.y;
    int b = bh >> 3, h = bh & 7;
    int n0 = blockIdx.x * 64;
    // kappa_h = 1 - exp(log(1/32) + h*(log(1/512)-log(1/32))/7)
    float kappa = 1.0f - __expf(-3.46573590f + (float)h * -0.39608410f);
    float logk = __logf(kappa);
    int tx = threadIdx.x, ty = threadIdx.y;
    int tid = ty * 16 + tx;
    size_t base = (size_t)(b * S_) * E_ + h * DH_;
    #pragma unroll
    for (int i = 0; i < 16; ++i) {
        int idx = tid + i * 256;               // 4096 elems
        Qs[idx >> 6][idx & 63] = Q[base + (size_t)(n0 + (idx >> 6)) * E_ + (idx & 63)];
    }
    float acc[4][4] = {};
    for (int m0 = 0; m0 <= n0 + 32; m0 += 32) {
        #pragma unroll
        for (int i = 0; i < 8; ++i) {
            int idx = tid + i * 256;           // 2048 elems
            int r = idx >> 6, d = idx & 63;
            size_t g = base + (size_t)(m0 + r) * E_ + d;
            Ks[r][d] = K[g];
            Vs[r][d] = V[g];
        }
        __syncthreads();                        // covers Qs on first iter too
        // S[n][m] = sum_d Q[n][d]*K[m][d]
        float sacc[4][2] = {};
        #pragma unroll 8
        for (int d = 0; d < 64; ++d) {
            float a[4], bq[2];
            #pragma unroll
            for (int i = 0; i < 4; ++i) a[i] = Qs[ty * 4 + i][d];
            #pragma unroll
            for (int j = 0; j < 2; ++j) bq[j] = Ks[tx * 2 + j][d];
            #pragma unroll
            for (int i = 0; i < 4; ++i)
                #pragma unroll
                for (int j = 0; j < 2; ++j)
                    sacc[i][j] = fmaf(a[i], bq[j], sacc[i][j]);
        }
        #pragma unroll
        for (int i = 0; i < 4; ++i)
            #pragma unroll
            for (int j = 0; j < 2; ++j) {
                int n = n0 + ty * 4 + i, m = m0 + tx * 2 + j;
                float w = (n >= m) ? __expf((float)(n - m) * logk) : 0.0f;
                Ss[ty * 4 + i][tx * 2 + j] = sacc[i][j] * w;
            }
        __syncthreads();
        // O[n][d] += sum_m S[n][m]*V[m][d]
        #pragma unroll 8
        for (int ml = 0; ml < 32; ++ml) {
            float sv[4], vv[4];
            #pragma unroll
            for (int i = 0; i < 4; ++i) sv[i] = Ss[ty * 4 + i][ml];
            #pragma unroll
            for (int j = 0; j < 4; ++j) vv[j] = Vs[ml][tx * 4 + j];
            #pragma unroll
            for (int i = 0; i < 4; ++i)
                #pragma unroll
                for (int j = 0; j < 4; ++j)
                    acc[i][j] = fmaf(sv[i], vv[j], acc[i][j]);
        }
        __syncthreads();
    }
    #pragma unroll
    for (int i = 0; i < 4; ++i)
        #pragma unroll
        for (int j = 0; j < 4; ++j)
            R[base + (size_t)(n0 + ty * 4 + i) * E_ + tx * 4 + j] = acc[i][j];
}

// ---------------------------------------------------------------------------
// GroupNorm with num_groups = H over feature axis: group = one wave (64 lanes).
__global__ __launch_bounds__(512) void groupnorm_k(float* __restrict__ Rb,
                                                   const float* __restrict__ gs,
                                                   const float* __restrict__ gb) {
    size_t row = blockIdx.x;                    // b*S + s
    int t = threadIdx.x;                        // 0..511 (feature)
    float v = Rb[row * E_ + t];
    float sum = v, sq = v * v;
    #pragma unroll
    for (int off = 1; off < 64; off <<= 1) {
        sum += __shfl_xor(sum, off, 64);
        sq  += __shfl_xor(sq,  off, 64);
    }
    float mean = sum * (1.0f / 64.0f);
    float var  = sq * (1.0f / 64.0f) - mean * mean;
    float ny = (v - mean) * rsqrtf(var + 1e-5f);
    Rb[row * E_ + t] = ny * gs[t] + gb[t];
}

// ---------------------------------------------------------------------------
// T = swish(G) * Rn   (elementwise), safe in-place on G.
__global__ __launch_bounds__(256) void swish_mul(const float* __restrict__ G,
                                                 const float* __restrict__ Rn,
                                                 float* __restrict__ T) {
    int i = blockIdx.x * 256 + threadIdx.x;
    float g = G[i];
    T[i] = g * Rn[i] / (1.0f + __expf(-g));
}

// ---------------------------------------------------------------------------
// out = rmsnorm(X + Y) * scale, eps = 1e-6, one row (E=512) per block.
__global__ __launch_bounds__(512) void rmsnorm_res(const float* __restrict__ X,
                                                   const float* __restrict__ Y,
                                                   const float* __restrict__ sc,
                                                   float* __restrict__ out) {
    __shared__ float part[8];
    size_t row = blockIdx.x;
    int t = threadIdx.x;
    float v = X[row * E_ + t] + Y[row * E_ + t];
    float sq = v * v;
    #pragma unroll
    for (int off = 1; off < 64; off <<= 1) sq += __shfl_xor(sq, off, 64);
    if ((t & 63) == 0) part[t >> 6] = sq;
    __syncthreads();
    float tot = 0.0f;
    #pragma unroll
    for (int i = 0; i < 8; ++i) tot += part[i];
    float r = rsqrtf(tot * (1.0f / 512.0f) + 1e-6f);
    out[row * E_ + t] = v * r * sc[t];
}

// ---------------------------------------------------------------------------
extern "C" void kernel_launch(void* const* d_in, const int* in_sizes, int n_in,
                              void* d_out, int out_size, void* d_ws, size_t ws_size,
                              hipStream_t stream) {
    const float* x    = (const float*)d_in[0];
    const float* obs  = (const float*)d_in[1];
    const float* wq1  = (const float*)d_in[2];
    const float* wk1  = (const float*)d_in[3];
    const float* wv1  = (const float*)d_in[4];
    const float* wg1  = (const float*)d_in[5];
    const float* wo1  = (const float*)d_in[6];
    const float* gs1  = (const float*)d_in[7];
    const float* gb1  = (const float*)d_in[8];
    const float* wq2  = (const float*)d_in[9];
    const float* wk2  = (const float*)d_in[10];
    const float* wv2  = (const float*)d_in[11];
    const float* wg2  = (const float*)d_in[12];
    const float* wo2  = (const float*)d_in[13];
    const float* gs2  = (const float*)d_in[14];
    const float* gb2  = (const float*)d_in[15];
    const float* ln1s = (const float*)d_in[16];
    const float* ln2s = (const float*)d_in[17];
    const float* ln3s = (const float*)d_in[18];
    const float* wlin = (const float*)d_in[19];
    const float* wgat = (const float*)d_in[20];
    const float* wout = (const float*)d_in[21];

    float* ws   = (float*)d_ws;
    float* Wq1p = ws;
    float* Wk1p = Wq1p + E_ * E_;
    float* Wv1p = Wk1p + E_ * E_;
    float* Wq2p = Wv1p + E_ * E_;
    float* Wk2p = Wq2p + E_ * E_;
    float* Wv2p = Wk2p + E_ * E_;
    float* buf0 = ws + 6 * E_ * E_;
    float* buf1 = buf0 + NTOT;
    float* buf2 = buf1 + NTOT;
    float* buf3 = buf2 + NTOT;
    float* buf4 = buf3 + NTOT;
    float* x1   = (float*)d_out;     // stage x1 in d_out; fully rewritten at end

    dim3 gB(E_ / 64, M_ / 64), tB(16, 16);
    dim3 gR(S_ / 64, B_ * H_);

    repack_w<<<1024, 256, 0, stream>>>(wq1, Wq1p);
    repack_w<<<1024, 256, 0, stream>>>(wk1, Wk1p);
    repack_w<<<1024, 256, 0, stream>>>(wv1, Wv1p);
    repack_w<<<1024, 256, 0, stream>>>(wq2, Wq2p);
    repack_w<<<1024, 256, 0, stream>>>(wk2, Wk2p);
    repack_w<<<1024, 256, 0, stream>>>(wv2, Wv2p);

    // ---- retention 1: key = query = value = x
    gemm_f32<<<gB, tB, 0, stream>>>(x, Wq1p, buf0);
    gemm_f32<<<gB, tB, 0, stream>>>(x, Wk1p, buf1);
    gemm_f32<<<gB, tB, 0, stream>>>(x, Wv1p, buf2);
    retention_f32<<<gR, tB, 0, stream>>>(buf0, buf1, buf2, buf3);
    groupnorm_k<<<M_, 512, 0, stream>>>(buf3, gs1, gb1);
    gemm_f32<<<gB, tB, 0, stream>>>(x, wg1, buf4);
    swish_mul<<<NTOT / 256, 256, 0, stream>>>(buf4, buf3, buf4);
    gemm_f32<<<gB, tB, 0, stream>>>(buf4, wo1, buf0);
    rmsnorm_res<<<M_, 512, 0, stream>>>(x, buf0, ln1s, x1);

    // ---- retention 2: key = value = x1, query = obs_rep
    gemm_f32<<<gB, tB, 0, stream>>>(obs, Wq2p, buf0);
    gemm_f32<<<gB, tB, 0, stream>>>(x1,  Wk2p, buf1);
    gemm_f32<<<gB, tB, 0, stream>>>(x1,  Wv2p, buf2);
    retention_f32<<<gR, tB, 0, stream>>>(buf0, buf1, buf2, buf3);
    groupnorm_k<<<M_, 512, 0, stream>>>(buf3, gs2, gb2);
    gemm_f32<<<gB, tB, 0, stream>>>(obs, wg2, buf4);
    swish_mul<<<NTOT / 256, 256, 0, stream>>>(buf4, buf3, buf4);
    gemm_f32<<<gB, tB, 0, stream>>>(buf4, wo2, buf0);
    rmsnorm_res<<<M_, 512, 0, stream>>>(obs, buf0, ln2s, buf1);   // x2 -> buf1

    // ---- FFN: out = rmsnorm(x2 + (swish(x2@Wg) * (x2@Wl)) @ Wo)
    gemm_f32<<<gB, tB, 0, stream>>>(buf1, wgat, buf0);
    gemm_f32<<<gB, tB, 0, stream>>>(buf1, wlin, buf2);
    swish_mul<<<NTOT / 256, 256, 0, stream>>>(buf0, buf2, buf0);
    gemm_f32<<<gB, tB, 0, stream>>>(buf0, wout, buf3);
    rmsnorm_res<<<M_, 512, 0, stream>>>(buf1, buf3, ln3s, (float*)d_out);
}

// Round 2
// 380.691 us; speedup vs baseline: 5.3075x; 5.3075x over previous
//
#include <hip/hip_runtime.h>
#include <hip/hip_bf16.h>
#include <stdint.h>

typedef unsigned short u16;
typedef unsigned int   u32;
typedef __bf16 bf16x8 __attribute__((ext_vector_type(8)));
typedef u16    u16x8  __attribute__((ext_vector_type(8)));
typedef float  f32x4  __attribute__((ext_vector_type(4)));

#define E_   512
#define H_   8
#define DH_  64
#define B_   8
#define S_   1024
#define M_   (B_ * S_)
#define NTOT (M_ * E_)

__device__ __forceinline__ u16 f2bf(float f) {
    u32 x = __float_as_uint(f);
    x += 0x7fffu + ((x >> 16) & 1u);
    return (u16)(x >> 16);
}
__device__ __forceinline__ bf16x8 as_bf(u16x8 v) {
    union { u16x8 u; bf16x8 b; } x; x.u = v; return x.b;
}

// ---------------------------------------------------------------------------
// bf16 MFMA GEMM: C[8192x512] = A[8192x512] @ B, with B given transposed
// (Bt[n][k], bf16). 128x128 tile, 4 waves (2x2), 64x64 per wave, K-step 64,
// double-buffered XOR-swizzled LDS. Output fp32 (Cf) or bf16 (Cb).
__global__ __launch_bounds__(256) void gemm_mfma(const u16* __restrict__ A,
                                                 const u16* __restrict__ Bt,
                                                 float* __restrict__ Cf,
                                                 u16* __restrict__ Cb) {
    __shared__ u16 Als[2][128 * 64];
    __shared__ u16 Bls[2][128 * 64];
    const int tid = threadIdx.x;
    const int l = tid & 63, w = tid >> 6;
    const int wm = w & 1, wn = w >> 1;
    const int bm = blockIdx.y * 128, bn = blockIdx.x * 128;

    const int srow = tid >> 3;     // +c*32
    const int sch  = tid & 7;
    int dstoff[4]; size_t srcA[4], srcB[4];
    #pragma unroll
    for (int c = 0; c < 4; ++c) {
        int row = c * 32 + srow;
        dstoff[c] = row * 128 + ((sch ^ (row & 7)) << 4);
        srcA[c] = (size_t)(bm + row) * E_ + sch * 8;
        srcB[c] = (size_t)(bn + row) * E_ + sch * 8;
    }
    int aoff[2][4], boff[2][4];
    #pragma unroll
    for (int kk = 0; kk < 2; ++kk)
        #pragma unroll
        for (int f = 0; f < 4; ++f) {
            int ra = wm * 64 + f * 16 + (l & 15);
            int rb = wn * 64 + f * 16 + (l & 15);
            int ch = kk * 4 + (l >> 4);
            aoff[kk][f] = ra * 128 + ((ch ^ (ra & 7)) << 4);
            boff[kk][f] = rb * 128 + ((ch ^ (rb & 7)) << 4);
        }

    f32x4 acc[4][4] = {};

    #pragma unroll
    for (int c = 0; c < 4; ++c) {
        *(uint4*)((char*)Als[0] + dstoff[c]) = *(const uint4*)(A + srcA[c]);
        *(uint4*)((char*)Bls[0] + dstoff[c]) = *(const uint4*)(Bt + srcB[c]);
    }
    __syncthreads();

    for (int t = 0; t < 8; ++t) {
        const int cur = t & 1;
        uint4 pa[4], pb[4];
        if (t < 7) {
            const int k1 = (t + 1) * 64;
            #pragma unroll
            for (int c = 0; c < 4; ++c) {
                pa[c] = *(const uint4*)(A + srcA[c] + k1);
                pb[c] = *(const uint4*)(Bt + srcB[c] + k1);
            }
        }
        #pragma unroll
        for (int kk = 0; kk < 2; ++kk) {
            bf16x8 af[4], bfr[4];
            #pragma unroll
            for (int f = 0; f < 4; ++f) {
                af[f]  = as_bf(*(const u16x8*)((const char*)Als[cur] + aoff[kk][f]));
                bfr[f] = as_bf(*(const u16x8*)((const char*)Bls[cur] + boff[kk][f]));
            }
            #pragma unroll
            for (int m = 0; m < 4; ++m)
                #pragma unroll
                for (int n = 0; n < 4; ++n)
                    acc[m][n] = __builtin_amdgcn_mfma_f32_16x16x32_bf16(af[m], bfr[n], acc[m][n], 0, 0, 0);
        }
        if (t < 7) {
            #pragma unroll
            for (int c = 0; c < 4; ++c) {
                *(uint4*)((char*)Als[cur ^ 1] + dstoff[c]) = pa[c];
                *(uint4*)((char*)Bls[cur ^ 1] + dstoff[c]) = pb[c];
            }
        }
        __syncthreads();
    }

    #pragma unroll
    for (int m = 0; m < 4; ++m) {
        int row = bm + wm * 64 + m * 16 + ((l >> 4) << 2);
        #pragma unroll
        for (int n = 0; n < 4; ++n) {
            int col = bn + wn * 64 + n * 16 + (l & 15);
            f32x4 v = acc[m][n];
            if (Cf) {
                #pragma unroll
                for (int r = 0; r < 4; ++r) Cf[(size_t)(row + r) * E_ + col] = v[r];
            } else {
                #pragma unroll
                for (int r = 0; r < 4; ++r) Cb[(size_t)(row + r) * E_ + col] = f2bf(v[r]);
            }
        }
    }
}

// ---------------------------------------------------------------------------
// MFMA retention. Per block: (bh, n-tile of 128). 4 waves, each owns 32 n-rows.
// QK^T computed as T = K@Q^T so the decay-weighted P packs into contiguous
// ds_write_b64 per lane. PV: A = P (LDS), B = V^T via swizzled scalar gather.
__global__ __launch_bounds__(256) void retention_mfma(const u16* __restrict__ Q,
                                                      const u16* __restrict__ K,
                                                      const u16* __restrict__ V,
                                                      float* __restrict__ R) {
    __shared__ u16 Qs[128 * 64], Ks[64 * 64], Vs[64 * 64], Ps[128 * 64];
    const int tid = threadIdx.x;
    const int l = tid & 63, w = tid >> 6;
    const int bh = blockIdx.y, h = bh & 7;
    const int nb = blockIdx.x, n0 = nb * 128;
    const size_t base = (size_t)(bh >> 3) * (S_ * E_) + h * DH_;

    const float kappa = 1.0f - __expf(-3.46573590f + (float)h * -0.39608410f);
    const float log2k = log2f(kappa);
    const float ik = 1.0f / kappa;
    const float ikp1 = ik, ikp2 = ik * ik, ikp3 = ik * ik * ik;

    const int srow = tid >> 3, sch = tid & 7;

    #pragma unroll
    for (int c = 0; c < 4; ++c) {
        int row = c * 32 + srow;
        *(uint4*)((char*)Qs + row * 128 + ((sch ^ (row & 7)) << 4)) =
            *(const uint4*)(Q + base + (size_t)(n0 + row) * E_ + sch * 8);
    }

    f32x4 acc[2][4] = {};
    const int ntiles = nb * 2 + 2;
    const int nmax = n0 + w * 32 + 31;

    for (int t = 0; t < ntiles; ++t) {
        const int m0 = t * 64;
        __syncthreads();
        #pragma unroll
        for (int c = 0; c < 2; ++c) {
            int row = c * 32 + srow;
            int dst = row * 128 + ((sch ^ (row & 7)) << 4);
            size_t src = base + (size_t)(m0 + row) * E_ + sch * 8;
            *(uint4*)((char*)Ks + dst) = *(const uint4*)(K + src);
            *(uint4*)((char*)Vs + dst) = *(const uint4*)(V + src);
        }
        __syncthreads();
        if (m0 > nmax) continue;   // fully masked for this wave; barriers stay uniform

        // ---- T = K @ Q^T (so lane's 4 regs = 4 consecutive m, fixed n)
        bf16x8 qf[2][2], kf[2][4];
        #pragma unroll
        for (int kk = 0; kk < 2; ++kk) {
            #pragma unroll
            for (int fn = 0; fn < 2; ++fn) {
                int row = w * 32 + fn * 16 + (l & 15);
                int ch = kk * 4 + (l >> 4);
                qf[kk][fn] = as_bf(*(const u16x8*)((const char*)Qs + row * 128 + ((ch ^ (row & 7)) << 4)));
            }
            #pragma unroll
            for (int fm = 0; fm < 4; ++fm) {
                int row = fm * 16 + (l & 15);
                int ch = kk * 4 + (l >> 4);
                kf[kk][fm] = as_bf(*(const u16x8*)((const char*)Ks + row * 128 + ((ch ^ (row & 7)) << 4)));
            }
        }
        f32x4 s[4][2] = {};
        #pragma unroll
        for (int kk = 0; kk < 2; ++kk)
            #pragma unroll
            for (int fm = 0; fm < 4; ++fm)
                #pragma unroll
                for (int fn = 0; fn < 2; ++fn)
                    s[fm][fn] = __builtin_amdgcn_mfma_f32_16x16x32_bf16(kf[kk][fm], qf[kk][fn], s[fm][fn], 0, 0, 0);

        // ---- decay weight + causal mask + bf16 pack -> Ps[n][m]
        #pragma unroll
        for (int fm = 0; fm < 4; ++fm) {
            #pragma unroll
            for (int fn = 0; fn < 2; ++fn) {
                int n_g  = n0 + w * 32 + fn * 16 + (l & 15);
                int mb_g = m0 + fm * 16 + ((l >> 4) << 2);
                int delta = n_g - mb_g;
                float wb = exp2f((float)delta * log2k);
                f32x4 v = s[fm][fn];
                float p0 = (delta >= 0) ? v[0] * wb : 0.f;
                float p1 = (delta >= 1) ? v[1] * wb * ikp1 : 0.f;
                float p2 = (delta >= 2) ? v[2] * wb * ikp2 : 0.f;
                float p3 = (delta >= 3) ? v[3] * wb * ikp3 : 0.f;
                int nl  = w * 32 + fn * 16 + (l & 15);
                int mbl = fm * 16 + ((l >> 4) << 2);
                int byteoff = nl * 128 + ((((mbl >> 3)) ^ (nl & 7)) << 4) + ((mbl & 7) << 1);
                uint2 pk;
                pk.x = (u32)f2bf(p0) | ((u32)f2bf(p1) << 16);
                pk.y = (u32)f2bf(p2) | ((u32)f2bf(p3) << 16);
                *(uint2*)((char*)Ps + byteoff) = pk;
            }
        }

        // ---- PV: acc[n][d] += P[n][m] * V[m][d]
        #pragma unroll
        for (int km = 0; km < 2; ++km) {
            bf16x8 pf[2];
            #pragma unroll
            for (int fn = 0; fn < 2; ++fn) {
                int row = w * 32 + fn * 16 + (l & 15);
                int ch = km * 4 + (l >> 4);
                pf[fn] = as_bf(*(const u16x8*)((const char*)Ps + row * 128 + ((ch ^ (row & 7)) << 4)));
            }
            #pragma unroll
            for (int fd = 0; fd < 4; ++fd) {
                int d = fd * 16 + (l & 15);
                int mbase = km * 32 + ((l >> 4) << 3);
                u16x8 vv;
                #pragma unroll
                for (int j = 0; j < 8; ++j) {
                    int m = mbase + j;
                    int idx = (m * 128 + (((d >> 3) ^ (m & 7)) << 4) + ((d & 7) << 1)) >> 1;
                    vv[j] = Vs[idx];
                }
                bf16x8 vfr = as_bf(vv);
                #pragma unroll
                for (int fn = 0; fn < 2; ++fn)
                    acc[fn][fd] = __builtin_amdgcn_mfma_f32_16x16x32_bf16(pf[fn], vfr, acc[fn][fd], 0, 0, 0);
            }
        }
    }

    #pragma unroll
    for (int fn = 0; fn < 2; ++fn) {
        int row = n0 + w * 32 + fn * 16 + ((l >> 4) << 2);
        #pragma unroll
        for (int fd = 0; fd < 4; ++fd) {
            int col = fd * 16 + (l & 15);
            f32x4 v = acc[fn][fd];
            #pragma unroll
            for (int r = 0; r < 4; ++r)
                R[base + (size_t)(row + r) * E_ + col] = v[r];
        }
    }
}

// ---------------------------------------------------------------------------
__global__ __launch_bounds__(512) void groupnorm_k(float* __restrict__ Rb,
                                                   const float* __restrict__ gs,
                                                   const float* __restrict__ gb) {
    size_t row = blockIdx.x;
    int t = threadIdx.x;
    float v = Rb[row * E_ + t];
    float sum = v, sq = v * v;
    #pragma unroll
    for (int off = 1; off < 64; off <<= 1) {
        sum += __shfl_xor(sum, off, 64);
        sq  += __shfl_xor(sq,  off, 64);
    }
    float mean = sum * (1.0f / 64.0f);
    float var  = sq * (1.0f / 64.0f) - mean * mean;
    float ny = (v - mean) * rsqrtf(var + 1e-5f);
    Rb[row * E_ + t] = ny * gs[t] + gb[t];
}

__global__ __launch_bounds__(256) void swish_mul_bf16(const float* __restrict__ G,
                                                      const float* __restrict__ Rn,
                                                      u16* __restrict__ T) {
    int i = blockIdx.x * 256 + threadIdx.x;
    float4 g = ((const float4*)G)[i];
    float4 r = ((const float4*)Rn)[i];
    ushort4 o;
    o.x = f2bf(g.x * r.x / (1.f + __expf(-g.x)));
    o.y = f2bf(g.y * r.y / (1.f + __expf(-g.y)));
    o.z = f2bf(g.z * r.z / (1.f + __expf(-g.z)));
    o.w = f2bf(g.w * r.w / (1.f + __expf(-g.w)));
    ((ushort4*)T)[i] = o;
}

__global__ __launch_bounds__(512) void rmsnorm_res(const float* __restrict__ X,
                                                   const float* __restrict__ Y,
                                                   const float* __restrict__ sc,
                                                   float* __restrict__ outf,
                                                   u16* __restrict__ outb) {
    __shared__ float part[8];
    size_t row = blockIdx.x;
    int t = threadIdx.x;
    float v = X[row * E_ + t] + Y[row * E_ + t];
    float sq = v * v;
    #pragma unroll
    for (int off = 1; off < 64; off <<= 1) sq += __shfl_xor(sq, off, 64);
    if ((t & 63) == 0) part[t >> 6] = sq;
    __syncthreads();
    float tot = 0.0f;
    #pragma unroll
    for (int i = 0; i < 8; ++i) tot += part[i];
    float r = rsqrtf(tot * (1.0f / 512.0f) + 1e-6f);
    float o = v * r * sc[t];
    if (outf) outf[row * E_ + t] = o;
    if (outb) outb[row * E_ + t] = f2bf(o);
}

__global__ __launch_bounds__(256) void cvt_bf16(const float* __restrict__ in,
                                                u16* __restrict__ out) {
    int i = blockIdx.x * 256 + threadIdx.x;
    float4 v = ((const float4*)in)[i];
    ushort4 o;
    o.x = f2bf(v.x); o.y = f2bf(v.y); o.z = f2bf(v.z); o.w = f2bf(v.w);
    ((ushort4*)out)[i] = o;
}

// (E,E) f32 row-major [k][n] -> bf16 [n][k]
__global__ __launch_bounds__(256) void transpose_w(const float* __restrict__ src,
                                                   u16* __restrict__ dst) {
    __shared__ float tle[64][65];
    int n0 = blockIdx.x * 64, k0 = blockIdx.y * 64;
    int tid = threadIdx.x;
    #pragma unroll
    for (int i = 0; i < 16; ++i) {
        int idx = i * 256 + tid;
        tle[idx >> 6][idx & 63] = src[(size_t)(k0 + (idx >> 6)) * E_ + n0 + (idx & 63)];
    }
    __syncthreads();
    #pragma unroll
    for (int i = 0; i < 16; ++i) {
        int idx = i * 256 + tid;
        dst[(size_t)(n0 + (idx >> 6)) * E_ + k0 + (idx & 63)] = f2bf(tle[idx & 63][idx >> 6]);
    }
}

// (H,E,DH) f32 -> bf16 [h*DH+d][e]
__global__ __launch_bounds__(256) void repack_qkv(const float* __restrict__ src,
                                                  u16* __restrict__ dst) {
    __shared__ float tle[64][65];
    int e0 = blockIdx.x * 64, h = blockIdx.y;
    int tid = threadIdx.x;
    #pragma unroll
    for (int i = 0; i < 16; ++i) {
        int idx = i * 256 + tid;
        tle[idx >> 6][idx & 63] = src[(size_t)h * E_ * DH_ + (size_t)(e0 + (idx >> 6)) * DH_ + (idx & 63)];
    }
    __syncthreads();
    #pragma unroll
    for (int i = 0; i < 16; ++i) {
        int idx = i * 256 + tid;
        dst[(size_t)(h * DH_ + (idx >> 6)) * E_ + e0 + (idx & 63)] = f2bf(tle[idx & 63][idx >> 6]);
    }
}

// ---------------------------------------------------------------------------
extern "C" void kernel_launch(void* const* d_in, const int* in_sizes, int n_in,
                              void* d_out, int out_size, void* d_ws, size_t ws_size,
                              hipStream_t stream) {
    const float* x    = (const float*)d_in[0];
    const float* obs  = (const float*)d_in[1];
    const float* wq1  = (const float*)d_in[2];
    const float* wk1  = (const float*)d_in[3];
    const float* wv1  = (const float*)d_in[4];
    const float* wg1  = (const float*)d_in[5];
    const float* wo1  = (const float*)d_in[6];
    const float* gs1  = (const float*)d_in[7];
    const float* gb1  = (const float*)d_in[8];
    const float* wq2  = (const float*)d_in[9];
    const float* wk2  = (const float*)d_in[10];
    const float* wv2  = (const float*)d_in[11];
    const float* wg2  = (const float*)d_in[12];
    const float* wo2  = (const float*)d_in[13];
    const float* gs2  = (const float*)d_in[14];
    const float* gb2  = (const float*)d_in[15];
    const float* ln1s = (const float*)d_in[16];
    const float* ln2s = (const float*)d_in[17];
    const float* ln3s = (const float*)d_in[18];
    const float* wlin = (const float*)d_in[19];
    const float* wgat = (const float*)d_in[20];
    const float* wout = (const float*)d_in[21];

    const size_t WSZ = (size_t)E_ * E_;         // elements per weight
    char* wsb = (char*)d_ws;
    u16* WQ1 = (u16*)wsb;
    u16* WK1 = WQ1 + WSZ;  u16* WV1 = WK1 + WSZ;
    u16* WG1 = WV1 + WSZ;  u16* WO1 = WG1 + WSZ;
    u16* WQ2 = WO1 + WSZ;  u16* WK2 = WQ2 + WSZ;
    u16* WV2 = WK2 + WSZ;  u16* WG2 = WV2 + WSZ;
    u16* WO2 = WG2 + WSZ;  u16* WGA = WO2 + WSZ;
    u16* WLI = WGA + WSZ;  u16* WOU = WLI + WSZ;
    u16* XB  = WOU + WSZ;                        // also X1B after stage 1
    u16* OB  = XB + NTOT;                        // also X2B after stage 2
    u16* QB  = OB + NTOT;
    u16* KB  = QB + NTOT;
    u16* VB  = KB + NTOT;
    u16* TB  = VB + NTOT;
    float* RF = (float*)(TB + NTOT);
    float* GF = RF + NTOT;
    float* X2F = (float*)d_out;                  // staged; rewritten in-place at end

    dim3 tG(256), gG(4, 64);                     // gemm
    dim3 gR(8, 64);                              // retention
    dim3 gT(8, 8);                               // transposes

    // ---- prep
    cvt_bf16<<<NTOT / 1024, 256, 0, stream>>>(x, XB);
    cvt_bf16<<<NTOT / 1024, 256, 0, stream>>>(obs, OB);
    repack_qkv<<<gT, 256, 0, stream>>>(wq1, WQ1);
    repack_qkv<<<gT, 256, 0, stream>>>(wk1, WK1);
    repack_qkv<<<gT, 256, 0, stream>>>(wv1, WV1);
    repack_qkv<<<gT, 256, 0, stream>>>(wq2, WQ2);
    repack_qkv<<<gT, 256, 0, stream>>>(wk2, WK2);
    repack_qkv<<<gT, 256, 0, stream>>>(wv2, WV2);
    transpose_w<<<gT, 256, 0, stream>>>(wg1, WG1);
    transpose_w<<<gT, 256, 0, stream>>>(wo1, WO1);
    transpose_w<<<gT, 256, 0, stream>>>(wg2, WG2);
    transpose_w<<<gT, 256, 0, stream>>>(wo2, WO2);
    transpose_w<<<gT, 256, 0, stream>>>(wgat, WGA);
    transpose_w<<<gT, 256, 0, stream>>>(wlin, WLI);
    transpose_w<<<gT, 256, 0, stream>>>(wout, WOU);

    // ---- stage 1: x1 = rmsnorm(x + msr(x,x,x))
    gemm_mfma<<<gG, tG, 0, stream>>>(XB, WQ1, nullptr, QB);
    gemm_mfma<<<gG, tG, 0, stream>>>(XB, WK1, nullptr, KB);
    gemm_mfma<<<gG, tG, 0, stream>>>(XB, WV1, nullptr, VB);
    retention_mfma<<<gR, tG, 0, stream>>>(QB, KB, VB, RF);
    groupnorm_k<<<M_, 512, 0, stream>>>(RF, gs1, gb1);
    gemm_mfma<<<gG, tG, 0, stream>>>(XB, WG1, GF, nullptr);
    swish_mul_bf16<<<NTOT / 1024, 256, 0, stream>>>(GF, RF, TB);
    gemm_mfma<<<gG, tG, 0, stream>>>(TB, WO1, GF, nullptr);
    rmsnorm_res<<<M_, 512, 0, stream>>>(x, GF, ln1s, nullptr, XB);   // X1B = XB

    // ---- stage 2: x2 = rmsnorm(obs + msr(x1, obs, x1))
    gemm_mfma<<<gG, tG, 0, stream>>>(OB, WQ2, nullptr, QB);
    gemm_mfma<<<gG, tG, 0, stream>>>(XB, WK2, nullptr, KB);
    gemm_mfma<<<gG, tG, 0, stream>>>(XB, WV2, nullptr, VB);
    retention_mfma<<<gR, tG, 0, stream>>>(QB, KB, VB, RF);
    groupnorm_k<<<M_, 512, 0, stream>>>(RF, gs2, gb2);
    gemm_mfma<<<gG, tG, 0, stream>>>(OB, WG2, GF, nullptr);
    swish_mul_bf16<<<NTOT / 1024, 256, 0, stream>>>(GF, RF, TB);
    gemm_mfma<<<gG, tG, 0, stream>>>(TB, WO2, GF, nullptr);
    rmsnorm_res<<<M_, 512, 0, stream>>>(obs, GF, ln2s, X2F, OB);     // X2B = OB

    // ---- FFN: out = rmsnorm(x2 + swiglu(x2))
    gemm_mfma<<<gG, tG, 0, stream>>>(OB, WGA, GF, nullptr);
    gemm_mfma<<<gG, tG, 0, stream>>>(OB, WLI, RF, nullptr);
    swish_mul_bf16<<<NTOT / 1024, 256, 0, stream>>>(GF, RF, TB);
    gemm_mfma<<<gG, tG, 0, stream>>>(TB, WOU, GF, nullptr);
    rmsnorm_res<<<M_, 512, 0, stream>>>(X2F, GF, ln3s, (float*)d_out, nullptr);
}

// Round 3
// 235.339 us; speedup vs baseline: 8.5856x; 1.6176x over previous
//
#include <hip/hip_runtime.h>
#include <hip/hip_bf16.h>
#include <stdint.h>

typedef unsigned short u16;
typedef unsigned int   u32;
typedef __bf16 bf16x8 __attribute__((ext_vector_type(8)));
typedef u16    u16x8  __attribute__((ext_vector_type(8)));
typedef float  f32x4  __attribute__((ext_vector_type(4)));

#define E_   512
#define H_   8
#define DH_  64
#define B_   8
#define S_   1024
#define M_   (B_ * S_)
#define NTOT (M_ * E_)

__device__ __forceinline__ u16 f2bf(float f) {
    u32 x = __float_as_uint(f);
    x += 0x7fffu + ((x >> 16) & 1u);
    return (u16)(x >> 16);
}
__device__ __forceinline__ float bf2f(u16 b) { return __uint_as_float((u32)b << 16); }
__device__ __forceinline__ bf16x8 as_bf(u16x8 v) {
    union { u16x8 u; bf16x8 b; } x; x.u = v; return x.b;
}

// ---------------------------------------------------------------------------
// All weight repacks/transposes fused. Output row-major [n][k] bf16, K=512.
// WC1/WC2: [2048][512] = rows {Q(512),K(512),V(512),G(512)}; WF: [1024][512]
// = {gate,lin}; WO1t/WO2t/WOUt: [512][512] transposed.
__global__ __launch_bounds__(256) void prep_weights(
    const float* __restrict__ wq1, const float* __restrict__ wk1, const float* __restrict__ wv1,
    const float* __restrict__ wg1, const float* __restrict__ wq2, const float* __restrict__ wk2,
    const float* __restrict__ wv2, const float* __restrict__ wg2, const float* __restrict__ wgat,
    const float* __restrict__ wlin, const float* __restrict__ wo1, const float* __restrict__ wo2,
    const float* __restrict__ wout,
    u16* __restrict__ WC1, u16* __restrict__ WC2, u16* __restrict__ WF,
    u16* __restrict__ WO1t, u16* __restrict__ WO2t, u16* __restrict__ WOUt) {
    __shared__ float tle[64][65];
    const int rt = blockIdx.y, c0 = blockIdx.x * 64, tid = threadIdx.x;
    u16* dst; const float* src; int lr0; bool qkv = false; int nb0 = 0, h = 0;
    if (rt < 64) {
        bool s1 = rt < 32;
        dst = s1 ? WC1 : WC2;
        int r = (rt & 31) * 64; lr0 = r;
        if (r < 1536) {
            qkv = true; h = (r >> 6) & 7;
            src = (r < 512) ? (s1 ? wq1 : wq2) : (r < 1024) ? (s1 ? wk1 : wk2) : (s1 ? wv1 : wv2);
        } else { src = s1 ? wg1 : wg2; nb0 = r - 1536; }
    } else if (rt < 80) {
        dst = WF; int r = (rt - 64) * 64; lr0 = r;
        src = (r < 512) ? wgat : wlin; nb0 = r & 511;
    } else if (rt < 88) { dst = WO1t; lr0 = (rt - 80) * 64; src = wo1; nb0 = lr0; }
    else if (rt < 96)   { dst = WO2t; lr0 = (rt - 88) * 64; src = wo2; nb0 = lr0; }
    else                { dst = WOUt; lr0 = (rt - 96) * 64; src = wout; nb0 = lr0; }

    #pragma unroll
    for (int i = 0; i < 16; ++i) {
        int idx = i * 256 + tid, a = idx >> 6, b = idx & 63;
        tle[a][b] = qkv ? src[(size_t)(h * 512 + c0 + a) * 64 + b]
                        : src[(size_t)(c0 + a) * 512 + nb0 + b];
    }
    __syncthreads();
    #pragma unroll
    for (int i = 0; i < 16; ++i) {
        int idx = i * 256 + tid;
        dst[(size_t)(lr0 + (idx >> 6)) * 512 + c0 + (idx & 63)] = f2bf(tle[idx & 63][idx >> 6]);
    }
}

// ---------------------------------------------------------------------------
__global__ __launch_bounds__(256) void cvt_both(const float* __restrict__ x,
                                                const float* __restrict__ obs,
                                                u16* __restrict__ XB, u16* __restrict__ OB) {
    int i = blockIdx.x * 256 + threadIdx.x;
    float4 v = ((const float4*)x)[i];
    ushort4 o;
    o.x = f2bf(v.x); o.y = f2bf(v.y); o.z = f2bf(v.z); o.w = f2bf(v.w);
    ((ushort4*)XB)[i] = o;
    v = ((const float4*)obs)[i];
    o.x = f2bf(v.x); o.y = f2bf(v.y); o.z = f2bf(v.z); o.w = f2bf(v.w);
    ((ushort4*)OB)[i] = o;
}

// ---------------------------------------------------------------------------
// Fused Q/K/V/G projection GEMM, N=2048 (col-blocks: 0-3 Q, 4-7 K, 8-11 V
// written TRANSPOSED to VT[bh][d][s], 12-15 G). Q,G read A1; K,V read A2.
__global__ __launch_bounds__(256) void gemm_qkvg(const u16* __restrict__ A1,
                                                 const u16* __restrict__ A2,
                                                 const u16* __restrict__ W,
                                                 u16* __restrict__ QB, u16* __restrict__ KB,
                                                 u16* __restrict__ VT, u16* __restrict__ GB) {
    __shared__ u16 Als[2][128 * 64];
    __shared__ u16 Bls[2][128 * 64];
    const int tid = threadIdx.x;
    const int l = tid & 63, w = tid >> 6;
    const int wm = w & 1, wn = w >> 1;
    const int bm = blockIdx.y * 128, bn = blockIdx.x * 128;
    const int which = blockIdx.x >> 2;
    const u16* A = (which == 1 || which == 2) ? A2 : A1;

    const int srow = tid >> 3, sch = tid & 7;
    int dstoff[4]; size_t srcA[4], srcB[4];
    #pragma unroll
    for (int c = 0; c < 4; ++c) {
        int row = c * 32 + srow;
        dstoff[c] = row * 128 + ((sch ^ (row & 7)) << 4);
        srcA[c] = (size_t)(bm + row) * E_ + sch * 8;
        srcB[c] = (size_t)(bn + row) * E_ + sch * 8;
    }
    int aoff[2][4], boff[2][4];
    #pragma unroll
    for (int kk = 0; kk < 2; ++kk)
        #pragma unroll
        for (int f = 0; f < 4; ++f) {
            int ra = wm * 64 + f * 16 + (l & 15);
            int rb = wn * 64 + f * 16 + (l & 15);
            int ch = kk * 4 + (l >> 4);
            aoff[kk][f] = ra * 128 + ((ch ^ (ra & 7)) << 4);
            boff[kk][f] = rb * 128 + ((ch ^ (rb & 7)) << 4);
        }

    f32x4 acc[4][4] = {};
    #pragma unroll
    for (int c = 0; c < 4; ++c) {
        *(uint4*)((char*)Als[0] + dstoff[c]) = *(const uint4*)(A + srcA[c]);
        *(uint4*)((char*)Bls[0] + dstoff[c]) = *(const uint4*)(W + srcB[c]);
    }
    __syncthreads();

    for (int t = 0; t < 8; ++t) {
        const int cur = t & 1;
        uint4 pa[4], pb[4];
        if (t < 7) {
            const int k1 = (t + 1) * 64;
            #pragma unroll
            for (int c = 0; c < 4; ++c) {
                pa[c] = *(const uint4*)(A + srcA[c] + k1);
                pb[c] = *(const uint4*)(W + srcB[c] + k1);
            }
        }
        #pragma unroll
        for (int kk = 0; kk < 2; ++kk) {
            bf16x8 af[4], bfr[4];
            #pragma unroll
            for (int f = 0; f < 4; ++f) {
                af[f]  = as_bf(*(const u16x8*)((const char*)Als[cur] + aoff[kk][f]));
                bfr[f] = as_bf(*(const u16x8*)((const char*)Bls[cur] + boff[kk][f]));
            }
            #pragma unroll
            for (int m = 0; m < 4; ++m)
                #pragma unroll
                for (int n = 0; n < 4; ++n)
                    acc[m][n] = __builtin_amdgcn_mfma_f32_16x16x32_bf16(af[m], bfr[n], acc[m][n], 0, 0, 0);
        }
        if (t < 7) {
            #pragma unroll
            for (int c = 0; c < 4; ++c) {
                *(uint4*)((char*)Als[cur ^ 1] + dstoff[c]) = pa[c];
                *(uint4*)((char*)Bls[cur ^ 1] + dstoff[c]) = pb[c];
            }
        }
        __syncthreads();
    }

    #pragma unroll
    for (int m = 0; m < 4; ++m) {
        int row = bm + wm * 64 + m * 16 + ((l >> 4) << 2);
        #pragma unroll
        for (int n = 0; n < 4; ++n) {
            int coll = (bn & 511) + wn * 64 + n * 16 + (l & 15);
            f32x4 v = acc[m][n];
            if (which == 2) {
                size_t va = (((size_t)(row >> 10) * 8 + (coll >> 6)) * 64 + (coll & 63)) * 1024
                            + (row & 1023);
                ushort4 o;
                o.x = f2bf(v[0]); o.y = f2bf(v[1]); o.z = f2bf(v[2]); o.w = f2bf(v[3]);
                *(ushort4*)(VT + va) = o;
            } else {
                u16* dst = (which == 0) ? QB : (which == 1) ? KB : GB;
                #pragma unroll
                for (int r = 0; r < 4; ++r) dst[(size_t)(row + r) * E_ + coll] = f2bf(v[r]);
            }
        }
    }
}

// ---------------------------------------------------------------------------
// Generic MFMA GEMM, K=512, N = gridDim.x*128, output stride ldc, f32 or bf16.
__global__ __launch_bounds__(256) void gemm_mfma(const u16* __restrict__ A,
                                                 const u16* __restrict__ W,
                                                 float* __restrict__ Cf,
                                                 u16* __restrict__ Cb, int ldc) {
    __shared__ u16 Als[2][128 * 64];
    __shared__ u16 Bls[2][128 * 64];
    const int tid = threadIdx.x;
    const int l = tid & 63, w = tid >> 6;
    const int wm = w & 1, wn = w >> 1;
    const int bm = blockIdx.y * 128, bn = blockIdx.x * 128;

    const int srow = tid >> 3, sch = tid & 7;
    int dstoff[4]; size_t srcA[4], srcB[4];
    #pragma unroll
    for (int c = 0; c < 4; ++c) {
        int row = c * 32 + srow;
        dstoff[c] = row * 128 + ((sch ^ (row & 7)) << 4);
        srcA[c] = (size_t)(bm + row) * E_ + sch * 8;
        srcB[c] = (size_t)(bn + row) * E_ + sch * 8;
    }
    int aoff[2][4], boff[2][4];
    #pragma unroll
    for (int kk = 0; kk < 2; ++kk)
        #pragma unroll
        for (int f = 0; f < 4; ++f) {
            int ra = wm * 64 + f * 16 + (l & 15);
            int rb = wn * 64 + f * 16 + (l & 15);
            int ch = kk * 4 + (l >> 4);
            aoff[kk][f] = ra * 128 + ((ch ^ (ra & 7)) << 4);
            boff[kk][f] = rb * 128 + ((ch ^ (rb & 7)) << 4);
        }

    f32x4 acc[4][4] = {};
    #pragma unroll
    for (int c = 0; c < 4; ++c) {
        *(uint4*)((char*)Als[0] + dstoff[c]) = *(const uint4*)(A + srcA[c]);
        *(uint4*)((char*)Bls[0] + dstoff[c]) = *(const uint4*)(W + srcB[c]);
    }
    __syncthreads();

    for (int t = 0; t < 8; ++t) {
        const int cur = t & 1;
        uint4 pa[4], pb[4];
        if (t < 7) {
            const int k1 = (t + 1) * 64;
            #pragma unroll
            for (int c = 0; c < 4; ++c) {
                pa[c] = *(const uint4*)(A + srcA[c] + k1);
                pb[c] = *(const uint4*)(W + srcB[c] + k1);
            }
        }
        #pragma unroll
        for (int kk = 0; kk < 2; ++kk) {
            bf16x8 af[4], bfr[4];
            #pragma unroll
            for (int f = 0; f < 4; ++f) {
                af[f]  = as_bf(*(const u16x8*)((const char*)Als[cur] + aoff[kk][f]));
                bfr[f] = as_bf(*(const u16x8*)((const char*)Bls[cur] + boff[kk][f]));
            }
            #pragma unroll
            for (int m = 0; m < 4; ++m)
                #pragma unroll
                for (int n = 0; n < 4; ++n)
                    acc[m][n] = __builtin_amdgcn_mfma_f32_16x16x32_bf16(af[m], bfr[n], acc[m][n], 0, 0, 0);
        }
        if (t < 7) {
            #pragma unroll
            for (int c = 0; c < 4; ++c) {
                *(uint4*)((char*)Als[cur ^ 1] + dstoff[c]) = pa[c];
                *(uint4*)((char*)Bls[cur ^ 1] + dstoff[c]) = pb[c];
            }
        }
        __syncthreads();
    }

    #pragma unroll
    for (int m = 0; m < 4; ++m) {
        int row = bm + wm * 64 + m * 16 + ((l >> 4) << 2);
        #pragma unroll
        for (int n = 0; n < 4; ++n) {
            int col = bn + wn * 64 + n * 16 + (l & 15);
            f32x4 v = acc[m][n];
            if (Cf) {
                #pragma unroll
                for (int r = 0; r < 4; ++r) Cf[(size_t)(row + r) * ldc + col] = v[r];
            } else {
                #pragma unroll
                for (int r = 0; r < 4; ++r) Cb[(size_t)(row + r) * ldc + col] = f2bf(v[r]);
            }
        }
    }
}

// ---------------------------------------------------------------------------
// Retention + GroupNorm + swish-gate fused.
// Grid: 512 blocks, work-balanced pairing (id, id+256) -> (nb, 7-nb).
// V supplied transposed: VT[bh][d][s]. Output T = swish(G)*GN(ret), bf16.
__global__ __launch_bounds__(256) void retention_fused(
        const u16* __restrict__ Q, const u16* __restrict__ K,
        const u16* __restrict__ VT, const u16* __restrict__ G,
        const float* __restrict__ gs, const float* __restrict__ gb,
        u16* __restrict__ T) {
    __shared__ u16 Qs[128 * 64], Ks[64 * 64], Vts[64 * 64], Ps[128 * 64];
    const int tid = threadIdx.x;
    const int l = tid & 63, w = tid >> 6;
    int id = blockIdx.x, nb, bh;
    if (id < 256) { nb = id & 7; bh = id >> 3; }
    else { int j = id - 256; nb = 7 - (j & 7); bh = 32 + (j >> 3); }
    const int h = bh & 7;
    const int n0 = nb * 128;
    const size_t base = (size_t)(bh >> 3) * (S_ * E_) + h * DH_;

    const float kappa = 1.0f - __expf(-3.46573590f + (float)h * -0.39608410f);
    const float log2k = log2f(kappa);
    const float ik = 1.0f / kappa;
    const float ikp2 = ik * ik, ikp3 = ik * ik * ik;

    float gsv[4], gbv[4];
    #pragma unroll
    for (int fd = 0; fd < 4; ++fd) {
        gsv[fd] = gs[h * 64 + fd * 16 + (l & 15)];
        gbv[fd] = gb[h * 64 + fd * 16 + (l & 15)];
    }

    const int srow = tid >> 3, sch = tid & 7;
    #pragma unroll
    for (int c = 0; c < 4; ++c) {
        int row = c * 32 + srow;
        *(uint4*)((char*)Qs + row * 128 + ((sch ^ (row & 7)) << 4)) =
            *(const uint4*)(Q + base + (size_t)(n0 + row) * E_ + sch * 8);
    }

    f32x4 acc[2][4] = {};
    const int ntiles = nb * 2 + 2;
    const int nmax = n0 + w * 32 + 31;

    for (int t = 0; t < ntiles; ++t) {
        const int m0 = t * 64;
        __syncthreads();
        #pragma unroll
        for (int c = 0; c < 2; ++c) {
            int row = c * 32 + srow;
            *(uint4*)((char*)Ks + row * 128 + ((sch ^ (row & 7)) << 4)) =
                *(const uint4*)(K + base + (size_t)(m0 + row) * E_ + sch * 8);
            // VT tile: rows d, cols m-local
            *(uint4*)((char*)Vts + row * 128 + ((sch ^ (row & 7)) << 4)) =
                *(const uint4*)(VT + ((size_t)bh * 64 + row) * 1024 + m0 + sch * 8);
        }
        __syncthreads();
        if (m0 > nmax) continue;

        // ---- T = K @ Q^T
        bf16x8 qf[2][2], kf[2][4];
        #pragma unroll
        for (int kk = 0; kk < 2; ++kk) {
            #pragma unroll
            for (int fn = 0; fn < 2; ++fn) {
                int row = w * 32 + fn * 16 + (l & 15);
                int ch = kk * 4 + (l >> 4);
                qf[kk][fn] = as_bf(*(const u16x8*)((const char*)Qs + row * 128 + ((ch ^ (row & 7)) << 4)));
            }
            #pragma unroll
            for (int fm = 0; fm < 4; ++fm) {
                int row = fm * 16 + (l & 15);
                int ch = kk * 4 + (l >> 4);
                kf[kk][fm] = as_bf(*(const u16x8*)((const char*)Ks + row * 128 + ((ch ^ (row & 7)) << 4)));
            }
        }
        f32x4 s[4][2] = {};
        #pragma unroll
        for (int kk = 0; kk < 2; ++kk)
            #pragma unroll
            for (int fm = 0; fm < 4; ++fm)
                #pragma unroll
                for (int fn = 0; fn < 2; ++fn)
                    s[fm][fn] = __builtin_amdgcn_mfma_f32_16x16x32_bf16(kf[kk][fm], qf[kk][fn], s[fm][fn], 0, 0, 0);

        // ---- decay + causal mask -> Ps[n][m] bf16
        #pragma unroll
        for (int fm = 0; fm < 4; ++fm) {
            #pragma unroll
            for (int fn = 0; fn < 2; ++fn) {
                int n_g  = n0 + w * 32 + fn * 16 + (l & 15);
                int mb_g = m0 + fm * 16 + ((l >> 4) << 2);
                int delta = n_g - mb_g;
                float wb = exp2f((float)delta * log2k);
                f32x4 v = s[fm][fn];
                float p0 = (delta >= 0) ? v[0] * wb : 0.f;
                float p1 = (delta >= 1) ? v[1] * wb * ik : 0.f;
                float p2 = (delta >= 2) ? v[2] * wb * ikp2 : 0.f;
                float p3 = (delta >= 3) ? v[3] * wb * ikp3 : 0.f;
                int nl  = w * 32 + fn * 16 + (l & 15);
                int mbl = fm * 16 + ((l >> 4) << 2);
                int byteoff = nl * 128 + ((((mbl >> 3)) ^ (nl & 7)) << 4) + ((mbl & 7) << 1);
                uint2 pk;
                pk.x = (u32)f2bf(p0) | ((u32)f2bf(p1) << 16);
                pk.y = (u32)f2bf(p2) | ((u32)f2bf(p3) << 16);
                *(uint2*)((char*)Ps + byteoff) = pk;
            }
        }

        // ---- PV: acc[n][d] += P[n][m] * V[m][d]; B-operand from Vts rows
        #pragma unroll
        for (int km = 0; km < 2; ++km) {
            bf16x8 pf[2];
            #pragma unroll
            for (int fn = 0; fn < 2; ++fn) {
                int row = w * 32 + fn * 16 + (l & 15);
                int ch = km * 4 + (l >> 4);
                pf[fn] = as_bf(*(const u16x8*)((const char*)Ps + row * 128 + ((ch ^ (row & 7)) << 4)));
            }
            #pragma unroll
            for (int fd = 0; fd < 4; ++fd) {
                int d = fd * 16 + (l & 15);
                int mch = km * 4 + (l >> 4);
                bf16x8 vfr = as_bf(*(const u16x8*)((const char*)Vts + d * 128 + ((mch ^ (d & 7)) << 4)));
                #pragma unroll
                for (int fn = 0; fn < 2; ++fn)
                    acc[fn][fd] = __builtin_amdgcn_mfma_f32_16x16x32_bf16(pf[fn], vfr, acc[fn][fd], 0, 0, 0);
            }
        }
    }

    // ---- fused GroupNorm (per row over this head's 64 dims) + swish gate
    #pragma unroll
    for (int fn = 0; fn < 2; ++fn) {
        #pragma unroll
        for (int r = 0; r < 4; ++r) {
            float s1 = 0.f, s2 = 0.f;
            #pragma unroll
            for (int fd = 0; fd < 4; ++fd) { float v = acc[fn][fd][r]; s1 += v; s2 += v * v; }
            #pragma unroll
            for (int off = 1; off < 16; off <<= 1) {
                s1 += __shfl_xor(s1, off, 64);
                s2 += __shfl_xor(s2, off, 64);
            }
            float mean = s1 * (1.f / 64.f);
            float var  = s2 * (1.f / 64.f) - mean * mean;
            float rinv = rsqrtf(var + 1e-5f);
            int rowg = n0 + w * 32 + fn * 16 + ((l >> 4) << 2) + r;
            size_t rb = base + (size_t)rowg * E_;
            #pragma unroll
            for (int fd = 0; fd < 4; ++fd) {
                int d = fd * 16 + (l & 15);
                float ny = (acc[fn][fd][r] - mean) * rinv;
                float rn = ny * gsv[fd] + gbv[fd];
                float g = bf2f(G[rb + d]);
                T[rb + d] = f2bf(g * rn / (1.f + __expf(-g)));
            }
        }
    }
}

// ---------------------------------------------------------------------------
// FFN: T = swish(gate) * lin, gate/lin packed in FB[row][0:512 | 512:1024].
__global__ __launch_bounds__(256) void swish_ffn(const u16* __restrict__ FB,
                                                 u16* __restrict__ T) {
    int i = blockIdx.x * 256 + threadIdx.x;
    int row = i >> 6, c8 = (i & 63) << 3;
    u16x8 gv = *(const u16x8*)(FB + (size_t)row * 1024 + c8);
    u16x8 lv = *(const u16x8*)(FB + (size_t)row * 1024 + 512 + c8);
    u16x8 o;
    #pragma unroll
    for (int j = 0; j < 8; ++j) {
        float g = bf2f(gv[j]), lvf = bf2f(lv[j]);
        o[j] = f2bf(g * lvf / (1.f + __expf(-g)));
    }
    *(u16x8*)(T + (size_t)row * 512 + c8) = o;
}

// ---------------------------------------------------------------------------
__global__ __launch_bounds__(512) void rmsnorm_res(const float* __restrict__ X,
                                                   const float* __restrict__ Y,
                                                   const float* __restrict__ sc,
                                                   float* __restrict__ outf,
                                                   u16* __restrict__ outb) {
    __shared__ float part[8];
    size_t row = blockIdx.x;
    int t = threadIdx.x;
    float v = X[row * E_ + t] + Y[row * E_ + t];
    float sq = v * v;
    #pragma unroll
    for (int off = 1; off < 64; off <<= 1) sq += __shfl_xor(sq, off, 64);
    if ((t & 63) == 0) part[t >> 6] = sq;
    __syncthreads();
    float tot = 0.0f;
    #pragma unroll
    for (int i = 0; i < 8; ++i) tot += part[i];
    float r = rsqrtf(tot * (1.0f / 512.0f) + 1e-6f);
    float o = v * r * sc[t];
    if (outf) outf[row * E_ + t] = o;
    if (outb) outb[row * E_ + t] = f2bf(o);
}

// ---------------------------------------------------------------------------
extern "C" void kernel_launch(void* const* d_in, const int* in_sizes, int n_in,
                              void* d_out, int out_size, void* d_ws, size_t ws_size,
                              hipStream_t stream) {
    const float* x    = (const float*)d_in[0];
    const float* obs  = (const float*)d_in[1];
    const float* wq1  = (const float*)d_in[2];
    const float* wk1  = (const float*)d_in[3];
    const float* wv1  = (const float*)d_in[4];
    const float* wg1  = (const float*)d_in[5];
    const float* wo1  = (const float*)d_in[6];
    const float* gs1  = (const float*)d_in[7];
    const float* gb1  = (const float*)d_in[8];
    const float* wq2  = (const float*)d_in[9];
    const float* wk2  = (const float*)d_in[10];
    const float* wv2  = (const float*)d_in[11];
    const float* wg2  = (const float*)d_in[12];
    const float* wo2  = (const float*)d_in[13];
    const float* gs2  = (const float*)d_in[14];
    const float* gb2  = (const float*)d_in[15];
    const float* ln1s = (const float*)d_in[16];
    const float* ln2s = (const float*)d_in[17];
    const float* ln3s = (const float*)d_in[18];
    const float* wlin = (const float*)d_in[19];
    const float* wgat = (const float*)d_in[20];
    const float* wout = (const float*)d_in[21];

    u16* wsb = (u16*)d_ws;
    u16* WC1  = wsb;                          // 2048*512
    u16* WC2  = WC1 + 2048 * 512;             // 2048*512
    u16* WF   = WC2 + 2048 * 512;             // 1024*512
    u16* WO1t = WF + 1024 * 512;              // 512*512
    u16* WO2t = WO1t + 512 * 512;
    u16* WOUt = WO2t + 512 * 512;
    u16* XB   = WOUt + 512 * 512;             // x bf16, later x1 bf16
    u16* OB   = XB + NTOT;                    // obs bf16, later x2 bf16
    u16* QB   = OB + NTOT;
    u16* KB   = QB + NTOT;
    u16* VT   = KB + NTOT;
    u16* GB   = VT + NTOT;
    u16* TB   = GB + NTOT;
    float* GF = (float*)QB;                   // WO-output f32, aliases QB+KB (free then)
    u16*  FB  = QB;                           // FFN gate|lin, aliases QB+KB (free then)
    float* X2F = (float*)d_out;               // staged x2 f32; rewritten at end

    dim3 tG(256);

    prep_weights<<<dim3(8, 104), tG, 0, stream>>>(wq1, wk1, wv1, wg1, wq2, wk2, wv2, wg2,
                                                  wgat, wlin, wo1, wo2, wout,
                                                  WC1, WC2, WF, WO1t, WO2t, WOUt);
    cvt_both<<<NTOT / 1024, tG, 0, stream>>>(x, obs, XB, OB);

    // ---- stage 1: x1 = rmsnorm(x + msr(x,x,x))
    gemm_qkvg<<<dim3(16, 64), tG, 0, stream>>>(XB, XB, WC1, QB, KB, VT, GB);
    retention_fused<<<512, tG, 0, stream>>>(QB, KB, VT, GB, gs1, gb1, TB);
    gemm_mfma<<<dim3(4, 64), tG, 0, stream>>>(TB, WO1t, GF, nullptr, E_);
    rmsnorm_res<<<M_, 512, 0, stream>>>(x, GF, ln1s, nullptr, XB);     // x1 -> XB

    // ---- stage 2: x2 = rmsnorm(obs + msr(key=x1, query=obs, value=x1))
    gemm_qkvg<<<dim3(16, 64), tG, 0, stream>>>(OB, XB, WC2, QB, KB, VT, GB);
    retention_fused<<<512, tG, 0, stream>>>(QB, KB, VT, GB, gs2, gb2, TB);
    gemm_mfma<<<dim3(4, 64), tG, 0, stream>>>(TB, WO2t, GF, nullptr, E_);
    rmsnorm_res<<<M_, 512, 0, stream>>>(obs, GF, ln2s, X2F, OB);       // x2 -> OB, X2F

    // ---- FFN: out = rmsnorm(x2 + (swish(x2@Wg)*(x2@Wl))@Wo)
    gemm_mfma<<<dim3(8, 64), tG, 0, stream>>>(OB, WF, nullptr, FB, 1024);
    swish_ffn<<<M_ * E_ / 8 / 256, tG, 0, stream>>>(FB, TB);
    gemm_mfma<<<dim3(4, 64), tG, 0, stream>>>(TB, WOUt, GF, nullptr, E_);
    rmsnorm_res<<<M_, 512, 0, stream>>>(X2F, GF, ln3s, (float*)d_out, nullptr);
}

// Round 4
// 230.147 us; speedup vs baseline: 8.7793x; 1.0226x over previous
//
#include <hip/hip_runtime.h>
#include <hip/hip_bf16.h>
#include <stdint.h>

typedef unsigned short u16;
typedef unsigned int   u32;
typedef __bf16 bf16x8 __attribute__((ext_vector_type(8)));
typedef u16    u16x8  __attribute__((ext_vector_type(8)));
typedef float  f32x4  __attribute__((ext_vector_type(4)));

#define E_   512
#define H_   8
#define DH_  64
#define B_   8
#define S_   1024
#define M_   (B_ * S_)
#define NTOT (M_ * E_)

__device__ __forceinline__ u16 f2bf(float f) {
    u32 x = __float_as_uint(f);
    x += 0x7fffu + ((x >> 16) & 1u);
    return (u16)(x >> 16);
}
__device__ __forceinline__ float bf2f(u16 b) { return __uint_as_float((u32)b << 16); }
__device__ __forceinline__ bf16x8 as_bf(u16x8 v) {
    union { u16x8 u; bf16x8 b; } x; x.u = v; return x.b;
}
// Direct global->LDS DMA, 16B per lane. LDS dest = wave-uniform base + lane*16.
__device__ __forceinline__ void gll16(const u16* g, u16* l) {
    __builtin_amdgcn_global_load_lds((const __attribute__((address_space(1))) u32*)g,
                                     (__attribute__((address_space(3))) u32*)l, 16, 0, 0);
}
// XCD-aware flat-id remap: each XCD owns a contiguous chunk of the grid.
__device__ __forceinline__ void xcd_map(int f, int nwg, int gx, int& bx, int& by) {
    int nf = (f & 7) * (nwg >> 3) + (f >> 3);
    bx = nf % gx; by = nf / gx;
}

// ---------------------------------------------------------------------------
// All weight repacks/transposes fused. Output row-major [n][k] bf16, K=512.
__global__ __launch_bounds__(256) void prep_weights(
    const float* __restrict__ wq1, const float* __restrict__ wk1, const float* __restrict__ wv1,
    const float* __restrict__ wg1, const float* __restrict__ wq2, const float* __restrict__ wk2,
    const float* __restrict__ wv2, const float* __restrict__ wg2, const float* __restrict__ wgat,
    const float* __restrict__ wlin, const float* __restrict__ wo1, const float* __restrict__ wo2,
    const float* __restrict__ wout,
    u16* __restrict__ WC1, u16* __restrict__ WC2, u16* __restrict__ WF,
    u16* __restrict__ WO1t, u16* __restrict__ WO2t, u16* __restrict__ WOUt) {
    __shared__ float tle[64][65];
    const int rt = blockIdx.y, c0 = blockIdx.x * 64, tid = threadIdx.x;
    u16* dst; const float* src; int lr0; bool qkv = false; int nb0 = 0, h = 0;
    if (rt < 64) {
        bool s1 = rt < 32;
        dst = s1 ? WC1 : WC2;
        int r = (rt & 31) * 64; lr0 = r;
        if (r < 1536) {
            qkv = true; h = (r >> 6) & 7;
            src = (r < 512) ? (s1 ? wq1 : wq2) : (r < 1024) ? (s1 ? wk1 : wk2) : (s1 ? wv1 : wv2);
        } else { src = s1 ? wg1 : wg2; nb0 = r - 1536; }
    } else if (rt < 80) {
        dst = WF; int r = (rt - 64) * 64; lr0 = r;
        src = (r < 512) ? wgat : wlin; nb0 = r & 511;
    } else if (rt < 88) { dst = WO1t; lr0 = (rt - 80) * 64; src = wo1; nb0 = lr0; }
    else if (rt < 96)   { dst = WO2t; lr0 = (rt - 88) * 64; src = wo2; nb0 = lr0; }
    else                { dst = WOUt; lr0 = (rt - 96) * 64; src = wout; nb0 = lr0; }

    #pragma unroll
    for (int i = 0; i < 16; ++i) {
        int idx = i * 256 + tid, a = idx >> 6, b = idx & 63;
        tle[a][b] = qkv ? src[(size_t)(h * 512 + c0 + a) * 64 + b]
                        : src[(size_t)(c0 + a) * 512 + nb0 + b];
    }
    __syncthreads();
    #pragma unroll
    for (int i = 0; i < 16; ++i) {
        int idx = i * 256 + tid;
        dst[(size_t)(lr0 + (idx >> 6)) * 512 + c0 + (idx & 63)] = f2bf(tle[idx & 63][idx >> 6]);
    }
}

// ---------------------------------------------------------------------------
__global__ __launch_bounds__(256) void cvt_both(const float* __restrict__ x,
                                                const float* __restrict__ obs,
                                                u16* __restrict__ XB, u16* __restrict__ OB) {
    int i = blockIdx.x * 256 + threadIdx.x;
    float4 v = ((const float4*)x)[i];
    ushort4 o;
    o.x = f2bf(v.x); o.y = f2bf(v.y); o.z = f2bf(v.z); o.w = f2bf(v.w);
    ((ushort4*)XB)[i] = o;
    v = ((const float4*)obs)[i];
    o.x = f2bf(v.x); o.y = f2bf(v.y); o.z = f2bf(v.z); o.w = f2bf(v.w);
    ((ushort4*)OB)[i] = o;
}

// ---------------------------------------------------------------------------
// Fused Q/K/V/G projection GEMM, flat grid 1024 (XCD-swizzled), col-blocks:
// 0-3 Q, 4-7 K, 8-11 V (written transposed to VT[bh][d][s]), 12-15 G.
// Staging via global_load_lds: linear LDS dest + inverse-swizzled source.
__global__ __launch_bounds__(256) void gemm_qkvg(const u16* __restrict__ A1,
                                                 const u16* __restrict__ A2,
                                                 const u16* __restrict__ W,
                                                 u16* __restrict__ QB, u16* __restrict__ KB,
                                                 u16* __restrict__ VT, u16* __restrict__ GB) {
    __shared__ u16 Als[2][128 * 64];
    __shared__ u16 Bls[2][128 * 64];
    const int tid = threadIdx.x;
    const int l = tid & 63, w = tid >> 6;
    const int wm = w & 1, wn = w >> 1;
    int bx, by; xcd_map(blockIdx.x, 1024, 16, bx, by);
    const int bm = by * 128, bn = bx * 128;
    const int which = bx >> 2;
    const u16* A = (which == 1 || which == 2) ? A2 : A1;

    // staging geometry: per c, wave w fills LDS bytes [c*4096 + w*1024, +1024)
    size_t srcA[4], srcB[4]; int ldst[4];
    #pragma unroll
    for (int c = 0; c < 4; ++c) {
        int row = c * 32 + w * 8 + (l >> 3);
        int chs = (l & 7) ^ (row & 7);
        srcA[c] = (size_t)(bm + row) * E_ + chs * 8;
        srcB[c] = (size_t)(bn + row) * E_ + chs * 8;
        ldst[c] = c * 2048 + w * 512;               // u16 elements, wave-uniform
    }
    int aoff[2][4], boff[2][4];
    #pragma unroll
    for (int kk = 0; kk < 2; ++kk)
        #pragma unroll
        for (int f = 0; f < 4; ++f) {
            int ra = wm * 64 + f * 16 + (l & 15);
            int rb = wn * 64 + f * 16 + (l & 15);
            int ch = kk * 4 + (l >> 4);
            aoff[kk][f] = ra * 128 + ((ch ^ (ra & 7)) << 4);
            boff[kk][f] = rb * 128 + ((ch ^ (rb & 7)) << 4);
        }

    f32x4 acc[4][4] = {};
    #pragma unroll
    for (int c = 0; c < 4; ++c) {
        gll16(A + srcA[c], &Als[0][ldst[c]]);
        gll16(W + srcB[c], &Bls[0][ldst[c]]);
    }
    __syncthreads();

    for (int t = 0; t < 8; ++t) {
        const int cur = t & 1;
        if (t < 7) {
            const int k1 = (t + 1) * 64;
            #pragma unroll
            for (int c = 0; c < 4; ++c) {
                gll16(A + srcA[c] + k1, &Als[cur ^ 1][ldst[c]]);
                gll16(W + srcB[c] + k1, &Bls[cur ^ 1][ldst[c]]);
            }
        }
        #pragma unroll
        for (int kk = 0; kk < 2; ++kk) {
            bf16x8 af[4], bfr[4];
            #pragma unroll
            for (int f = 0; f < 4; ++f) {
                af[f]  = as_bf(*(const u16x8*)((const char*)Als[cur] + aoff[kk][f]));
                bfr[f] = as_bf(*(const u16x8*)((const char*)Bls[cur] + boff[kk][f]));
            }
            #pragma unroll
            for (int m = 0; m < 4; ++m)
                #pragma unroll
                for (int n = 0; n < 4; ++n)
                    acc[m][n] = __builtin_amdgcn_mfma_f32_16x16x32_bf16(af[m], bfr[n], acc[m][n], 0, 0, 0);
        }
        __syncthreads();
    }

    #pragma unroll
    for (int m = 0; m < 4; ++m) {
        int row = bm + wm * 64 + m * 16 + ((l >> 4) << 2);
        #pragma unroll
        for (int n = 0; n < 4; ++n) {
            int coll = ((bn & 511)) + wn * 64 + n * 16 + (l & 15);
            f32x4 v = acc[m][n];
            if (which == 2) {
                size_t va = (((size_t)(row >> 10) * 8 + (coll >> 6)) * 64 + (coll & 63)) * 1024
                            + (row & 1023);
                ushort4 o;
                o.x = f2bf(v[0]); o.y = f2bf(v[1]); o.z = f2bf(v[2]); o.w = f2bf(v[3]);
                *(ushort4*)(VT + va) = o;
            } else {
                u16* dst = (which == 0) ? QB : (which == 1) ? KB : GB;
                #pragma unroll
                for (int r = 0; r < 4; ++r) dst[(size_t)(row + r) * E_ + coll] = f2bf(v[r]);
            }
        }
    }
}

// ---------------------------------------------------------------------------
// Generic MFMA GEMM, K=512, flat XCD-swizzled grid, N = gx*128, stride ldc.
__global__ __launch_bounds__(256) void gemm_mfma(const u16* __restrict__ A,
                                                 const u16* __restrict__ W,
                                                 float* __restrict__ Cf,
                                                 u16* __restrict__ Cb, int ldc, int gx) {
    __shared__ u16 Als[2][128 * 64];
    __shared__ u16 Bls[2][128 * 64];
    const int tid = threadIdx.x;
    const int l = tid & 63, w = tid >> 6;
    const int wm = w & 1, wn = w >> 1;
    int bx, by; xcd_map(blockIdx.x, gridDim.x, gx, bx, by);
    const int bm = by * 128, bn = bx * 128;

    size_t srcA[4], srcB[4]; int ldst[4];
    #pragma unroll
    for (int c = 0; c < 4; ++c) {
        int row = c * 32 + w * 8 + (l >> 3);
        int chs = (l & 7) ^ (row & 7);
        srcA[c] = (size_t)(bm + row) * E_ + chs * 8;
        srcB[c] = (size_t)(bn + row) * E_ + chs * 8;
        ldst[c] = c * 2048 + w * 512;
    }
    int aoff[2][4], boff[2][4];
    #pragma unroll
    for (int kk = 0; kk < 2; ++kk)
        #pragma unroll
        for (int f = 0; f < 4; ++f) {
            int ra = wm * 64 + f * 16 + (l & 15);
            int rb = wn * 64 + f * 16 + (l & 15);
            int ch = kk * 4 + (l >> 4);
            aoff[kk][f] = ra * 128 + ((ch ^ (ra & 7)) << 4);
            boff[kk][f] = rb * 128 + ((ch ^ (rb & 7)) << 4);
        }

    f32x4 acc[4][4] = {};
    #pragma unroll
    for (int c = 0; c < 4; ++c) {
        gll16(A + srcA[c], &Als[0][ldst[c]]);
        gll16(W + srcB[c], &Bls[0][ldst[c]]);
    }
    __syncthreads();

    for (int t = 0; t < 8; ++t) {
        const int cur = t & 1;
        if (t < 7) {
            const int k1 = (t + 1) * 64;
            #pragma unroll
            for (int c = 0; c < 4; ++c) {
                gll16(A + srcA[c] + k1, &Als[cur ^ 1][ldst[c]]);
                gll16(W + srcB[c] + k1, &Bls[cur ^ 1][ldst[c]]);
            }
        }
        #pragma unroll
        for (int kk = 0; kk < 2; ++kk) {
            bf16x8 af[4], bfr[4];
            #pragma unroll
            for (int f = 0; f < 4; ++f) {
                af[f]  = as_bf(*(const u16x8*)((const char*)Als[cur] + aoff[kk][f]));
                bfr[f] = as_bf(*(const u16x8*)((const char*)Bls[cur] + boff[kk][f]));
            }
            #pragma unroll
            for (int m = 0; m < 4; ++m)
                #pragma unroll
                for (int n = 0; n < 4; ++n)
                    acc[m][n] = __builtin_amdgcn_mfma_f32_16x16x32_bf16(af[m], bfr[n], acc[m][n], 0, 0, 0);
        }
        __syncthreads();
    }

    #pragma unroll
    for (int m = 0; m < 4; ++m) {
        int row = bm + wm * 64 + m * 16 + ((l >> 4) << 2);
        #pragma unroll
        for (int n = 0; n < 4; ++n) {
            int col = bn + wn * 64 + n * 16 + (l & 15);
            f32x4 v = acc[m][n];
            if (Cf) {
                #pragma unroll
                for (int r = 0; r < 4; ++r) Cf[(size_t)(row + r) * ldc + col] = v[r];
            } else {
                #pragma unroll
                for (int r = 0; r < 4; ++r) Cb[(size_t)(row + r) * ldc + col] = f2bf(v[r]);
            }
        }
    }
}

// ---------------------------------------------------------------------------
// Retention + GroupNorm + swish-gate fused. V supplied transposed VT[bh][d][s].
// Staging via global_load_lds (linear dest + inverse-swizzled source).
__global__ __launch_bounds__(256) void retention_fused(
        const u16* __restrict__ Q, const u16* __restrict__ K,
        const u16* __restrict__ VT, const u16* __restrict__ G,
        const float* __restrict__ gs, const float* __restrict__ gb,
        u16* __restrict__ T) {
    __shared__ u16 Qs[128 * 64], Ks[64 * 64], Vts[64 * 64], Ps[128 * 64];
    const int tid = threadIdx.x;
    const int l = tid & 63, w = tid >> 6;
    int id = blockIdx.x, nb, bh;
    if (id < 256) { nb = id & 7; bh = id >> 3; }
    else { int j = id - 256; nb = 7 - (j & 7); bh = 32 + (j >> 3); }
    const int h = bh & 7;
    const int n0 = nb * 128;
    const size_t base = (size_t)(bh >> 3) * (S_ * E_) + h * DH_;

    const float kappa = 1.0f - __expf(-3.46573590f + (float)h * -0.39608410f);
    const float log2k = log2f(kappa);
    const float ik = 1.0f / kappa;
    const float ikp2 = ik * ik, ikp3 = ik * ik * ik;

    float gsv[4], gbv[4];
    #pragma unroll
    for (int fd = 0; fd < 4; ++fd) {
        gsv[fd] = gs[h * 64 + fd * 16 + (l & 15)];
        gbv[fd] = gb[h * 64 + fd * 16 + (l & 15)];
    }

    // staging geometry (shared by Q(4c), K/VT(2c))
    int srow[4], schs[4], sdst[4];
    #pragma unroll
    for (int c = 0; c < 4; ++c) {
        srow[c] = c * 32 + w * 8 + (l >> 3);
        schs[c] = (l & 7) ^ (srow[c] & 7);
        sdst[c] = c * 2048 + w * 512;
    }
    #pragma unroll
    for (int c = 0; c < 4; ++c)
        gll16(Q + base + (size_t)(n0 + srow[c]) * E_ + schs[c] * 8, &Qs[sdst[c]]);

    f32x4 acc[2][4] = {};
    const int ntiles = nb * 2 + 2;
    const int nmax = n0 + w * 32 + 31;

    for (int t = 0; t < ntiles; ++t) {
        const int m0 = t * 64;
        __syncthreads();
        #pragma unroll
        for (int c = 0; c < 2; ++c) {
            gll16(K + base + (size_t)(m0 + srow[c]) * E_ + schs[c] * 8, &Ks[sdst[c]]);
            gll16(VT + ((size_t)bh * 64 + srow[c]) * 1024 + m0 + schs[c] * 8, &Vts[sdst[c]]);
        }
        __syncthreads();
        if (m0 > nmax) continue;

        // ---- T = K @ Q^T
        bf16x8 qf[2][2], kf[2][4];
        #pragma unroll
        for (int kk = 0; kk < 2; ++kk) {
            #pragma unroll
            for (int fn = 0; fn < 2; ++fn) {
                int row = w * 32 + fn * 16 + (l & 15);
                int ch = kk * 4 + (l >> 4);
                qf[kk][fn] = as_bf(*(const u16x8*)((const char*)Qs + row * 128 + ((ch ^ (row & 7)) << 4)));
            }
            #pragma unroll
            for (int fm = 0; fm < 4; ++fm) {
                int row = fm * 16 + (l & 15);
                int ch = kk * 4 + (l >> 4);
                kf[kk][fm] = as_bf(*(const u16x8*)((const char*)Ks + row * 128 + ((ch ^ (row & 7)) << 4)));
            }
        }
        f32x4 s[4][2] = {};
        #pragma unroll
        for (int kk = 0; kk < 2; ++kk)
            #pragma unroll
            for (int fm = 0; fm < 4; ++fm)
                #pragma unroll
                for (int fn = 0; fn < 2; ++fn)
                    s[fm][fn] = __builtin_amdgcn_mfma_f32_16x16x32_bf16(kf[kk][fm], qf[kk][fn], s[fm][fn], 0, 0, 0);

        // ---- decay + causal mask -> Ps[n][m] bf16
        #pragma unroll
        for (int fm = 0; fm < 4; ++fm) {
            #pragma unroll
            for (int fn = 0; fn < 2; ++fn) {
                int n_g  = n0 + w * 32 + fn * 16 + (l & 15);
                int mb_g = m0 + fm * 16 + ((l >> 4) << 2);
                int delta = n_g - mb_g;
                float wb = exp2f((float)delta * log2k);
                f32x4 v = s[fm][fn];
                float p0 = (delta >= 0) ? v[0] * wb : 0.f;
                float p1 = (delta >= 1) ? v[1] * wb * ik : 0.f;
                float p2 = (delta >= 2) ? v[2] * wb * ikp2 : 0.f;
                float p3 = (delta >= 3) ? v[3] * wb * ikp3 : 0.f;
                int nl  = w * 32 + fn * 16 + (l & 15);
                int mbl = fm * 16 + ((l >> 4) << 2);
                int byteoff = nl * 128 + ((((mbl >> 3)) ^ (nl & 7)) << 4) + ((mbl & 7) << 1);
                uint2 pk;
                pk.x = (u32)f2bf(p0) | ((u32)f2bf(p1) << 16);
                pk.y = (u32)f2bf(p2) | ((u32)f2bf(p3) << 16);
                *(uint2*)((char*)Ps + byteoff) = pk;
            }
        }

        // ---- PV: acc[n][d] += P[n][m] * V[m][d]
        #pragma unroll
        for (int km = 0; km < 2; ++km) {
            bf16x8 pf[2];
            #pragma unroll
            for (int fn = 0; fn < 2; ++fn) {
                int row = w * 32 + fn * 16 + (l & 15);
                int ch = km * 4 + (l >> 4);
                pf[fn] = as_bf(*(const u16x8*)((const char*)Ps + row * 128 + ((ch ^ (row & 7)) << 4)));
            }
            #pragma unroll
            for (int fd = 0; fd < 4; ++fd) {
                int d = fd * 16 + (l & 15);
                int mch = km * 4 + (l >> 4);
                bf16x8 vfr = as_bf(*(const u16x8*)((const char*)Vts + d * 128 + ((mch ^ (d & 7)) << 4)));
                #pragma unroll
                for (int fn = 0; fn < 2; ++fn)
                    acc[fn][fd] = __builtin_amdgcn_mfma_f32_16x16x32_bf16(pf[fn], vfr, acc[fn][fd], 0, 0, 0);
            }
        }
    }

    // ---- fused GroupNorm + swish gate
    #pragma unroll
    for (int fn = 0; fn < 2; ++fn) {
        #pragma unroll
        for (int r = 0; r < 4; ++r) {
            float s1 = 0.f, s2 = 0.f;
            #pragma unroll
            for (int fd = 0; fd < 4; ++fd) { float v = acc[fn][fd][r]; s1 += v; s2 += v * v; }
            #pragma unroll
            for (int off = 1; off < 16; off <<= 1) {
                s1 += __shfl_xor(s1, off, 64);
                s2 += __shfl_xor(s2, off, 64);
            }
            float mean = s1 * (1.f / 64.f);
            float var  = s2 * (1.f / 64.f) - mean * mean;
            float rinv = rsqrtf(var + 1e-5f);
            int rowg = n0 + w * 32 + fn * 16 + ((l >> 4) << 2) + r;
            size_t rb = base + (size_t)rowg * E_;
            #pragma unroll
            for (int fd = 0; fd < 4; ++fd) {
                int d = fd * 16 + (l & 15);
                float ny = (acc[fn][fd][r] - mean) * rinv;
                float rn = ny * gsv[fd] + gbv[fd];
                float g = bf2f(G[rb + d]);
                T[rb + d] = f2bf(g * rn / (1.f + __expf(-g)));
            }
        }
    }
}

// ---------------------------------------------------------------------------
__global__ __launch_bounds__(256) void swish_ffn(const u16* __restrict__ FB,
                                                 u16* __restrict__ T) {
    int i = blockIdx.x * 256 + threadIdx.x;
    int row = i >> 6, c8 = (i & 63) << 3;
    u16x8 gv = *(const u16x8*)(FB + (size_t)row * 1024 + c8);
    u16x8 lv = *(const u16x8*)(FB + (size_t)row * 1024 + 512 + c8);
    u16x8 o;
    #pragma unroll
    for (int j = 0; j < 8; ++j) {
        float g = bf2f(gv[j]), lvf = bf2f(lv[j]);
        o[j] = f2bf(g * lvf / (1.f + __expf(-g)));
    }
    *(u16x8*)(T + (size_t)row * 512 + c8) = o;
}

// ---------------------------------------------------------------------------
__global__ __launch_bounds__(512) void rmsnorm_res(const float* __restrict__ X,
                                                   const float* __restrict__ Y,
                                                   const float* __restrict__ sc,
                                                   float* __restrict__ outf,
                                                   u16* __restrict__ outb) {
    __shared__ float part[8];
    size_t row = blockIdx.x;
    int t = threadIdx.x;
    float v = X[row * E_ + t] + Y[row * E_ + t];
    float sq = v * v;
    #pragma unroll
    for (int off = 1; off < 64; off <<= 1) sq += __shfl_xor(sq, off, 64);
    if ((t & 63) == 0) part[t >> 6] = sq;
    __syncthreads();
    float tot = 0.0f;
    #pragma unroll
    for (int i = 0; i < 8; ++i) tot += part[i];
    float r = rsqrtf(tot * (1.0f / 512.0f) + 1e-6f);
    float o = v * r * sc[t];
    if (outf) outf[row * E_ + t] = o;
    if (outb) outb[row * E_ + t] = f2bf(o);
}

// ---------------------------------------------------------------------------
extern "C" void kernel_launch(void* const* d_in, const int* in_sizes, int n_in,
                              void* d_out, int out_size, void* d_ws, size_t ws_size,
                              hipStream_t stream) {
    const float* x    = (const float*)d_in[0];
    const float* obs  = (const float*)d_in[1];
    const float* wq1  = (const float*)d_in[2];
    const float* wk1  = (const float*)d_in[3];
    const float* wv1  = (const float*)d_in[4];
    const float* wg1  = (const float*)d_in[5];
    const float* wo1  = (const float*)d_in[6];
    const float* gs1  = (const float*)d_in[7];
    const float* gb1  = (const float*)d_in[8];
    const float* wq2  = (const float*)d_in[9];
    const float* wk2  = (const float*)d_in[10];
    const float* wv2  = (const float*)d_in[11];
    const float* wg2  = (const float*)d_in[12];
    const float* wo2  = (const float*)d_in[13];
    const float* gs2  = (const float*)d_in[14];
    const float* gb2  = (const float*)d_in[15];
    const float* ln1s = (const float*)d_in[16];
    const float* ln2s = (const float*)d_in[17];
    const float* ln3s = (const float*)d_in[18];
    const float* wlin = (const float*)d_in[19];
    const float* wgat = (const float*)d_in[20];
    const float* wout = (const float*)d_in[21];

    u16* wsb = (u16*)d_ws;
    u16* WC1  = wsb;
    u16* WC2  = WC1 + 2048 * 512;
    u16* WF   = WC2 + 2048 * 512;
    u16* WO1t = WF + 1024 * 512;
    u16* WO2t = WO1t + 512 * 512;
    u16* WOUt = WO2t + 512 * 512;
    u16* XB   = WOUt + 512 * 512;
    u16* OB   = XB + NTOT;
    u16* QB   = OB + NTOT;
    u16* KB   = QB + NTOT;
    u16* VT   = KB + NTOT;
    u16* GB   = VT + NTOT;
    u16* TB   = GB + NTOT;
    float* GF = (float*)QB;
    u16*  FB  = QB;
    float* X2F = (float*)d_out;

    dim3 tG(256);

    prep_weights<<<dim3(8, 104), tG, 0, stream>>>(wq1, wk1, wv1, wg1, wq2, wk2, wv2, wg2,
                                                  wgat, wlin, wo1, wo2, wout,
                                                  WC1, WC2, WF, WO1t, WO2t, WOUt);
    cvt_both<<<NTOT / 1024, tG, 0, stream>>>(x, obs, XB, OB);

    // ---- stage 1
    gemm_qkvg<<<1024, tG, 0, stream>>>(XB, XB, WC1, QB, KB, VT, GB);
    retention_fused<<<512, tG, 0, stream>>>(QB, KB, VT, GB, gs1, gb1, TB);
    gemm_mfma<<<256, tG, 0, stream>>>(TB, WO1t, GF, nullptr, E_, 4);
    rmsnorm_res<<<M_, 512, 0, stream>>>(x, GF, ln1s, nullptr, XB);

    // ---- stage 2
    gemm_qkvg<<<1024, tG, 0, stream>>>(OB, XB, WC2, QB, KB, VT, GB);
    retention_fused<<<512, tG, 0, stream>>>(QB, KB, VT, GB, gs2, gb2, TB);
    gemm_mfma<<<256, tG, 0, stream>>>(TB, WO2t, GF, nullptr, E_, 4);
    rmsnorm_res<<<M_, 512, 0, stream>>>(obs, GF, ln2s, X2F, OB);

    // ---- FFN
    gemm_mfma<<<512, tG, 0, stream>>>(OB, WF, nullptr, FB, 1024, 8);
    swish_ffn<<<M_ * E_ / 8 / 256, tG, 0, stream>>>(FB, TB);
    gemm_mfma<<<256, tG, 0, stream>>>(TB, WOUt, GF, nullptr, E_, 4);
    rmsnorm_res<<<M_, 512, 0, stream>>>(X2F, GF, ln3s, (float*)d_out, nullptr);
}

// Round 5
// 210.890 us; speedup vs baseline: 9.5810x; 1.0913x over previous
//
#include <hip/hip_runtime.h>
#include <hip/hip_bf16.h>
#include <stdint.h>

typedef unsigned short u16;
typedef unsigned int   u32;
typedef __bf16 bf16x8 __attribute__((ext_vector_type(8)));
typedef u16    u16x8  __attribute__((ext_vector_type(8)));
typedef float  f32x4  __attribute__((ext_vector_type(4)));

#define E_   512
#define H_   8
#define DH_  64
#define B_   8
#define S_   1024
#define M_   (B_ * S_)
#define NTOT (M_ * E_)

__device__ __forceinline__ u16 f2bf(float f) {
    u32 x = __float_as_uint(f);
    x += 0x7fffu + ((x >> 16) & 1u);
    return (u16)(x >> 16);
}
__device__ __forceinline__ float bf2f(u16 b) { return __uint_as_float((u32)b << 16); }
__device__ __forceinline__ bf16x8 as_bf(u16x8 v) {
    union { u16x8 u; bf16x8 b; } x; x.u = v; return x.b;
}
__device__ __forceinline__ u32 cvtpk(float lo, float hi) {
    u32 r;
    asm("v_cvt_pk_bf16_f32 %0, %1, %2" : "=v"(r) : "v"(lo), "v"(hi));
    return r;
}
__device__ __forceinline__ void gll16(const u16* g, u16* l) {
    __builtin_amdgcn_global_load_lds((const __attribute__((address_space(1))) u32*)g,
                                     (__attribute__((address_space(3))) u32*)l, 16, 0, 0);
}
__device__ __forceinline__ void xcd_map(int f, int nwg, int gx, int& bx, int& by) {
    int nf = (f & 7) * (nwg >> 3) + (f >> 3);
    bx = nf % gx; by = nf / gx;
}

// ---------------------------------------------------------------------------
__global__ __launch_bounds__(256) void prep_weights(
    const float* __restrict__ wq1, const float* __restrict__ wk1, const float* __restrict__ wv1,
    const float* __restrict__ wg1, const float* __restrict__ wq2, const float* __restrict__ wk2,
    const float* __restrict__ wv2, const float* __restrict__ wg2, const float* __restrict__ wgat,
    const float* __restrict__ wlin, const float* __restrict__ wo1, const float* __restrict__ wo2,
    const float* __restrict__ wout,
    u16* __restrict__ WC1, u16* __restrict__ WC2, u16* __restrict__ WF,
    u16* __restrict__ WO1t, u16* __restrict__ WO2t, u16* __restrict__ WOUt) {
    __shared__ float tle[64][65];
    const int rt = blockIdx.y, c0 = blockIdx.x * 64, tid = threadIdx.x;
    u16* dst; const float* src; int lr0; bool qkv = false; int nb0 = 0, h = 0;
    if (rt < 64) {
        bool s1 = rt < 32;
        dst = s1 ? WC1 : WC2;
        int r = (rt & 31) * 64; lr0 = r;
        if (r < 1536) {
            qkv = true; h = (r >> 6) & 7;
            src = (r < 512) ? (s1 ? wq1 : wq2) : (r < 1024) ? (s1 ? wk1 : wk2) : (s1 ? wv1 : wv2);
        } else { src = s1 ? wg1 : wg2; nb0 = r - 1536; }
    } else if (rt < 80) {
        dst = WF; int r = (rt - 64) * 64; lr0 = r;
        src = (r < 512) ? wgat : wlin; nb0 = r & 511;
    } else if (rt < 88) { dst = WO1t; lr0 = (rt - 80) * 64; src = wo1; nb0 = lr0; }
    else if (rt < 96)   { dst = WO2t; lr0 = (rt - 88) * 64; src = wo2; nb0 = lr0; }
    else                { dst = WOUt; lr0 = (rt - 96) * 64; src = wout; nb0 = lr0; }

    #pragma unroll
    for (int i = 0; i < 16; ++i) {
        int idx = i * 256 + tid, a = idx >> 6, b = idx & 63;
        tle[a][b] = qkv ? src[(size_t)(h * 512 + c0 + a) * 64 + b]
                        : src[(size_t)(c0 + a) * 512 + nb0 + b];
    }
    __syncthreads();
    #pragma unroll
    for (int i = 0; i < 16; ++i) {
        int idx = i * 256 + tid;
        dst[(size_t)(lr0 + (idx >> 6)) * 512 + c0 + (idx & 63)] = f2bf(tle[idx & 63][idx >> 6]);
    }
}

// ---------------------------------------------------------------------------
__global__ __launch_bounds__(256) void cvt_both(const float* __restrict__ x,
                                                const float* __restrict__ obs,
                                                u16* __restrict__ XB, u16* __restrict__ OB) {
    int i = blockIdx.x * 256 + threadIdx.x;
    float4 v = ((const float4*)x)[i];
    ushort4 o;
    o.x = f2bf(v.x); o.y = f2bf(v.y); o.z = f2bf(v.z); o.w = f2bf(v.w);
    ((ushort4*)XB)[i] = o;
    v = ((const float4*)obs)[i];
    o.x = f2bf(v.x); o.y = f2bf(v.y); o.z = f2bf(v.z); o.w = f2bf(v.w);
    ((ushort4*)OB)[i] = o;
}

// ---------------------------------------------------------------------------
// Fused Q/K/V/G projection GEMM. 128x128 tile, single-buffer LDS (32KB),
// m97 structure: 2 barriers per K-step, global_load_lds staging.
__global__ __launch_bounds__(256) void gemm_qkvg(const u16* __restrict__ A1,
                                                 const u16* __restrict__ A2,
                                                 const u16* __restrict__ W,
                                                 u16* __restrict__ QB, u16* __restrict__ KB,
                                                 u16* __restrict__ VT, u16* __restrict__ GB) {
    __shared__ u16 Als[128 * 64];
    __shared__ u16 Bls[128 * 64];
    const int tid = threadIdx.x;
    const int l = tid & 63, w = tid >> 6;
    const int wm = w & 1, wn = w >> 1;
    int bx, by; xcd_map(blockIdx.x, 1024, 16, bx, by);
    const int bm = by * 128, bn = bx * 128;
    const int which = bx >> 2;
    const u16* A = (which == 1 || which == 2) ? A2 : A1;

    size_t srcA[4], srcB[4]; int ldst[4];
    #pragma unroll
    for (int c = 0; c < 4; ++c) {
        int row = c * 32 + w * 8 + (l >> 3);
        int chs = (l & 7) ^ (row & 7);
        srcA[c] = (size_t)(bm + row) * E_ + chs * 8;
        srcB[c] = (size_t)(bn + row) * E_ + chs * 8;
        ldst[c] = c * 2048 + w * 512;
    }
    int aoff[2][4], boff[2][4];
    #pragma unroll
    for (int kk = 0; kk < 2; ++kk)
        #pragma unroll
        for (int f = 0; f < 4; ++f) {
            int ra = wm * 64 + f * 16 + (l & 15);
            int rb = wn * 64 + f * 16 + (l & 15);
            int ch = kk * 4 + (l >> 4);
            aoff[kk][f] = ra * 128 + ((ch ^ (ra & 7)) << 4);
            boff[kk][f] = rb * 128 + ((ch ^ (rb & 7)) << 4);
        }

    f32x4 acc[4][4] = {};
    for (int t = 0; t < 8; ++t) {
        const int k1 = t * 64;
        #pragma unroll
        for (int c = 0; c < 4; ++c) {
            gll16(A + srcA[c] + k1, &Als[ldst[c]]);
            gll16(W + srcB[c] + k1, &Bls[ldst[c]]);
        }
        __syncthreads();
        #pragma unroll
        for (int kk = 0; kk < 2; ++kk) {
            bf16x8 af[4], bfr[4];
            #pragma unroll
            for (int f = 0; f < 4; ++f) {
                af[f]  = as_bf(*(const u16x8*)((const char*)Als + aoff[kk][f]));
                bfr[f] = as_bf(*(const u16x8*)((const char*)Bls + boff[kk][f]));
            }
            #pragma unroll
            for (int m = 0; m < 4; ++m)
                #pragma unroll
                for (int n = 0; n < 4; ++n)
                    acc[m][n] = __builtin_amdgcn_mfma_f32_16x16x32_bf16(af[m], bfr[n], acc[m][n], 0, 0, 0);
        }
        __syncthreads();
    }

    #pragma unroll
    for (int m = 0; m < 4; ++m) {
        int row = bm + wm * 64 + m * 16 + ((l >> 4) << 2);
        #pragma unroll
        for (int n = 0; n < 4; ++n) {
            int coll = (bn & 511) + wn * 64 + n * 16 + (l & 15);
            f32x4 v = acc[m][n];
            if (which == 2) {
                size_t va = (((size_t)(row >> 10) * 8 + (coll >> 6)) * 64 + (coll & 63)) * 1024
                            + (row & 1023);
                ushort4 o;
                o.x = f2bf(v[0]); o.y = f2bf(v[1]); o.z = f2bf(v[2]); o.w = f2bf(v[3]);
                *(ushort4*)(VT + va) = o;
            } else {
                u16* dst = (which == 0) ? QB : (which == 1) ? KB : GB;
                #pragma unroll
                for (int r = 0; r < 4; ++r) dst[(size_t)(row + r) * E_ + coll] = f2bf(v[r]);
            }
        }
    }
}

// ---------------------------------------------------------------------------
// 64x128-tile GEMM (N=512), f32 out. Single-buffer, m97 structure. Grid 512.
__global__ __launch_bounds__(256) void gemm_wo(const u16* __restrict__ A,
                                               const u16* __restrict__ W,
                                               float* __restrict__ Cf) {
    __shared__ u16 Als[64 * 64];
    __shared__ u16 Bls[128 * 64];
    const int tid = threadIdx.x;
    const int l = tid & 63, w = tid >> 6;
    const int wm = w & 1, wn = w >> 1;
    int bx, by; xcd_map(blockIdx.x, 512, 4, bx, by);
    const int bm = by * 64, bn = bx * 128;

    size_t srcA[2], srcB[4]; int ldstA[2], ldstB[4];
    #pragma unroll
    for (int c = 0; c < 4; ++c) {
        int row = c * 32 + w * 8 + (l >> 3);
        int chs = (l & 7) ^ (row & 7);
        if (c < 2) { srcA[c] = (size_t)(bm + row) * E_ + chs * 8; ldstA[c] = c * 2048 + w * 512; }
        srcB[c] = (size_t)(bn + row) * E_ + chs * 8;
        ldstB[c] = c * 2048 + w * 512;
    }
    int aoff[2][2], boff[2][4];
    #pragma unroll
    for (int kk = 0; kk < 2; ++kk) {
        #pragma unroll
        for (int f = 0; f < 2; ++f) {
            int ra = wm * 32 + f * 16 + (l & 15);
            aoff[kk][f] = ra * 128 + (((kk * 4 + (l >> 4)) ^ (ra & 7)) << 4);
        }
        #pragma unroll
        for (int f = 0; f < 4; ++f) {
            int rb = wn * 64 + f * 16 + (l & 15);
            boff[kk][f] = rb * 128 + (((kk * 4 + (l >> 4)) ^ (rb & 7)) << 4);
        }
    }

    f32x4 acc[2][4] = {};
    for (int t = 0; t < 8; ++t) {
        const int k1 = t * 64;
        #pragma unroll
        for (int c = 0; c < 2; ++c) gll16(A + srcA[c] + k1, &Als[ldstA[c]]);
        #pragma unroll
        for (int c = 0; c < 4; ++c) gll16(W + srcB[c] + k1, &Bls[ldstB[c]]);
        __syncthreads();
        #pragma unroll
        for (int kk = 0; kk < 2; ++kk) {
            bf16x8 af[2], bfr[4];
            #pragma unroll
            for (int f = 0; f < 2; ++f) af[f] = as_bf(*(const u16x8*)((const char*)Als + aoff[kk][f]));
            #pragma unroll
            for (int f = 0; f < 4; ++f) bfr[f] = as_bf(*(const u16x8*)((const char*)Bls + boff[kk][f]));
            #pragma unroll
            for (int m = 0; m < 2; ++m)
                #pragma unroll
                for (int n = 0; n < 4; ++n)
                    acc[m][n] = __builtin_amdgcn_mfma_f32_16x16x32_bf16(af[m], bfr[n], acc[m][n], 0, 0, 0);
        }
        __syncthreads();
    }

    #pragma unroll
    for (int m = 0; m < 2; ++m) {
        int row = bm + wm * 32 + m * 16 + ((l >> 4) << 2);
        #pragma unroll
        for (int n = 0; n < 4; ++n) {
            int col = bn + wn * 64 + n * 16 + (l & 15);
            f32x4 v = acc[m][n];
            #pragma unroll
            for (int r = 0; r < 4; ++r) Cf[(size_t)(row + r) * E_ + col] = v[r];
        }
    }
}

// ---------------------------------------------------------------------------
// FFN fused GEMM: per block computes gate-tile AND lin-tile (same out cols),
// epilogue does swish(gate)*lin -> bf16 T. 64x(64+64) tiles, grid 1024.
__global__ __launch_bounds__(256) void gemm_ffn(const u16* __restrict__ A,
                                                const u16* __restrict__ W,
                                                u16* __restrict__ T) {
    __shared__ u16 Als[64 * 64];
    __shared__ u16 Bgs[64 * 64];
    __shared__ u16 Bls[64 * 64];
    const int tid = threadIdx.x;
    const int l = tid & 63, w = tid >> 6;
    const int wm = w & 1, wn = w >> 1;
    int bx, by; xcd_map(blockIdx.x, 1024, 8, bx, by);
    const int bm = by * 64, bn = bx * 64;

    size_t srcA[2], srcG[2], srcL[2]; int ldst[2];
    #pragma unroll
    for (int c = 0; c < 2; ++c) {
        int row = c * 32 + w * 8 + (l >> 3);
        int chs = (l & 7) ^ (row & 7);
        srcA[c] = (size_t)(bm + row) * E_ + chs * 8;
        srcG[c] = (size_t)(bn + row) * E_ + chs * 8;
        srcL[c] = (size_t)(512 + bn + row) * E_ + chs * 8;
        ldst[c] = c * 2048 + w * 512;
    }
    int aoff[2][2], goff[2][2];
    #pragma unroll
    for (int kk = 0; kk < 2; ++kk)
        #pragma unroll
        for (int f = 0; f < 2; ++f) {
            int ra = wm * 32 + f * 16 + (l & 15);
            int rb = wn * 32 + f * 16 + (l & 15);
            aoff[kk][f] = ra * 128 + (((kk * 4 + (l >> 4)) ^ (ra & 7)) << 4);
            goff[kk][f] = rb * 128 + (((kk * 4 + (l >> 4)) ^ (rb & 7)) << 4);
        }

    f32x4 accg[2][2] = {}, accl[2][2] = {};
    for (int t = 0; t < 8; ++t) {
        const int k1 = t * 64;
        #pragma unroll
        for (int c = 0; c < 2; ++c) {
            gll16(A + srcA[c] + k1, &Als[ldst[c]]);
            gll16(W + srcG[c] + k1, &Bgs[ldst[c]]);
            gll16(W + srcL[c] + k1, &Bls[ldst[c]]);
        }
        __syncthreads();
        #pragma unroll
        for (int kk = 0; kk < 2; ++kk) {
            bf16x8 af[2], bg[2], bl[2];
            #pragma unroll
            for (int f = 0; f < 2; ++f) {
                af[f] = as_bf(*(const u16x8*)((const char*)Als + aoff[kk][f]));
                bg[f] = as_bf(*(const u16x8*)((const char*)Bgs + goff[kk][f]));
                bl[f] = as_bf(*(const u16x8*)((const char*)Bls + goff[kk][f]));
            }
            #pragma unroll
            for (int m = 0; m < 2; ++m)
                #pragma unroll
                for (int n = 0; n < 2; ++n) {
                    accg[m][n] = __builtin_amdgcn_mfma_f32_16x16x32_bf16(af[m], bg[n], accg[m][n], 0, 0, 0);
                    accl[m][n] = __builtin_amdgcn_mfma_f32_16x16x32_bf16(af[m], bl[n], accl[m][n], 0, 0, 0);
                }
        }
        __syncthreads();
    }

    #pragma unroll
    for (int m = 0; m < 2; ++m) {
        int row = bm + wm * 32 + m * 16 + ((l >> 4) << 2);
        #pragma unroll
        for (int n = 0; n < 2; ++n) {
            int col = bn + wn * 32 + n * 16 + (l & 15);
            #pragma unroll
            for (int r = 0; r < 4; ++r) {
                float g = accg[m][n][r], lv = accl[m][n][r];
                T[(size_t)(row + r) * E_ + col] = f2bf(g * lv / (1.f + __expf(-g)));
            }
        }
    }
}

// ---------------------------------------------------------------------------
// Retention + GroupNorm + swish-gate fused. m-tiles of 128, single-buffered.
__global__ __launch_bounds__(256) void retention_fused(
        const u16* __restrict__ Q, const u16* __restrict__ K,
        const u16* __restrict__ VT, const u16* __restrict__ G,
        const float* __restrict__ gs, const float* __restrict__ gb,
        u16* __restrict__ T) {
    __shared__ u16 Qs[128 * 64], Ks[128 * 64], Vts[64 * 128], Ps[128 * 128];
    const int tid = threadIdx.x;
    const int l = tid & 63, w = tid >> 6;
    int id = blockIdx.x, nb, bh;
    if (id < 256) { nb = id & 7; bh = id >> 3; }
    else { int j = id - 256; nb = 7 - (j & 7); bh = 32 + (j >> 3); }
    const int h = bh & 7;
    const int n0 = nb * 128;
    const size_t base = (size_t)(bh >> 3) * (S_ * E_) + h * DH_;

    const float kappa = 1.0f - __expf(-3.46573590f + (float)h * -0.39608410f);
    const float log2k = log2f(kappa);
    const float ik = 1.0f / kappa;
    const float ikp2 = ik * ik, ikp3 = ik * ik * ik;

    float gsv[4], gbv[4];
    #pragma unroll
    for (int fd = 0; fd < 4; ++fd) {
        gsv[fd] = gs[h * 64 + fd * 16 + (l & 15)];
        gbv[fd] = gb[h * 64 + fd * 16 + (l & 15)];
    }

    // ---- stage Q (128x64) once
    {
        #pragma unroll
        for (int c = 0; c < 4; ++c) {
            int row = c * 32 + w * 8 + (l >> 3);
            int chs = (l & 7) ^ (row & 7);
            gll16(Q + base + (size_t)(n0 + row) * E_ + chs * 8, &Qs[c * 2048 + w * 512]);
        }
    }
    __syncthreads();
    // Q fragments held in registers for the whole kernel
    bf16x8 qf[2][2];
    #pragma unroll
    for (int kk = 0; kk < 2; ++kk)
        #pragma unroll
        for (int fn = 0; fn < 2; ++fn) {
            int row = w * 32 + fn * 16 + (l & 15);
            int ch = kk * 4 + (l >> 4);
            qf[kk][fn] = as_bf(*(const u16x8*)((const char*)Qs + row * 128 + ((ch ^ (row & 7)) << 4)));
        }

    f32x4 acc[2][4] = {};
    const int nmin = n0 + w * 32;
    const int nmax = nmin + 31;

    for (int t = 0; t <= nb; ++t) {
        const int m0 = t * 128;
        __syncthreads();
        // stage K (128 rows x 64 d) and VT (64 d x 128 m)
        #pragma unroll
        for (int c = 0; c < 4; ++c) {
            int row = c * 32 + w * 8 + (l >> 3);
            int chs = (l & 7) ^ (row & 7);
            gll16(K + base + (size_t)(m0 + row) * E_ + chs * 8, &Ks[c * 2048 + w * 512]);
            int d = c * 16 + w * 4 + (l >> 4);
            int vch = (l & 15) ^ (d & 7);
            gll16(VT + ((size_t)bh * 64 + d) * 1024 + m0 + vch * 8, &Vts[c * 2048 + w * 512]);
        }
        __syncthreads();
        if (m0 > nmax) continue;
        const bool inter = (nmin >= m0 + 127);

        // ---- QK^T (as K@Q^T) + decay + pack, in two fm-halves
        #pragma unroll
        for (int fmh = 0; fmh < 2; ++fmh) {
            bf16x8 kf[2][4];
            #pragma unroll
            for (int kk = 0; kk < 2; ++kk)
                #pragma unroll
                for (int f = 0; f < 4; ++f) {
                    int row = (fmh * 4 + f) * 16 + (l & 15);
                    int ch = kk * 4 + (l >> 4);
                    kf[kk][f] = as_bf(*(const u16x8*)((const char*)Ks + row * 128 + ((ch ^ (row & 7)) << 4)));
                }
            f32x4 s[4][2] = {};
            __builtin_amdgcn_s_setprio(1);
            #pragma unroll
            for (int kk = 0; kk < 2; ++kk)
                #pragma unroll
                for (int f = 0; f < 4; ++f)
                    #pragma unroll
                    for (int fn = 0; fn < 2; ++fn)
                        s[f][fn] = __builtin_amdgcn_mfma_f32_16x16x32_bf16(kf[kk][f], qf[kk][fn], s[f][fn], 0, 0, 0);
            __builtin_amdgcn_s_setprio(0);

            #pragma unroll
            for (int f = 0; f < 4; ++f) {
                int fm = fmh * 4 + f;
                #pragma unroll
                for (int fn = 0; fn < 2; ++fn) {
                    int n_g  = n0 + w * 32 + fn * 16 + (l & 15);
                    int mb_g = m0 + fm * 16 + ((l >> 4) << 2);
                    int delta = n_g - mb_g;
                    float wb = exp2f((float)delta * log2k);
                    f32x4 v = s[f][fn];
                    float p0, p1, p2, p3;
                    if (inter) {
                        float w1 = wb * ik, w2 = w1 * ik, w3 = w2 * ik;
                        p0 = v[0] * wb; p1 = v[1] * w1; p2 = v[2] * w2; p3 = v[3] * w3;
                    } else {
                        p0 = (delta >= 0) ? v[0] * wb : 0.f;
                        p1 = (delta >= 1) ? v[1] * wb * ik : 0.f;
                        p2 = (delta >= 2) ? v[2] * wb * ikp2 : 0.f;
                        p3 = (delta >= 3) ? v[3] * wb * ikp3 : 0.f;
                    }
                    int nl  = w * 32 + fn * 16 + (l & 15);
                    int mbl = fm * 16 + ((l >> 4) << 2);
                    int byteoff = nl * 256 + ((((mbl >> 3)) ^ (nl & 7)) << 4) + ((mbl & 4) << 1);
                    uint2 pk;
                    pk.x = cvtpk(p0, p1);
                    pk.y = cvtpk(p2, p3);
                    *(uint2*)((char*)Ps + byteoff) = pk;
                }
            }
        }

        // ---- PV: acc[n][d] += P[n][m] * V[m][d]
        #pragma unroll
        for (int km = 0; km < 4; ++km) {
            bf16x8 pf[2];
            #pragma unroll
            for (int fn = 0; fn < 2; ++fn) {
                int row = w * 32 + fn * 16 + (l & 15);
                int ch = km * 4 + (l >> 4);
                pf[fn] = as_bf(*(const u16x8*)((const char*)Ps + row * 256 + ((ch ^ (row & 7)) << 4)));
            }
            __builtin_amdgcn_s_setprio(1);
            #pragma unroll
            for (int fd = 0; fd < 4; ++fd) {
                int d = fd * 16 + (l & 15);
                int mch = km * 4 + (l >> 4);
                bf16x8 vfr = as_bf(*(const u16x8*)((const char*)Vts + d * 256 + ((mch ^ (d & 7)) << 4)));
                #pragma unroll
                for (int fn = 0; fn < 2; ++fn)
                    acc[fn][fd] = __builtin_amdgcn_mfma_f32_16x16x32_bf16(pf[fn], vfr, acc[fn][fd], 0, 0, 0);
            }
            __builtin_amdgcn_s_setprio(0);
        }
    }

    // ---- fused GroupNorm + swish gate
    #pragma unroll
    for (int fn = 0; fn < 2; ++fn) {
        #pragma unroll
        for (int r = 0; r < 4; ++r) {
            float s1 = 0.f, s2 = 0.f;
            #pragma unroll
            for (int fd = 0; fd < 4; ++fd) { float v = acc[fn][fd][r]; s1 += v; s2 += v * v; }
            #pragma unroll
            for (int off = 1; off < 16; off <<= 1) {
                s1 += __shfl_xor(s1, off, 64);
                s2 += __shfl_xor(s2, off, 64);
            }
            float mean = s1 * (1.f / 64.f);
            float var  = s2 * (1.f / 64.f) - mean * mean;
            float rinv = rsqrtf(var + 1e-5f);
            int rowg = n0 + w * 32 + fn * 16 + ((l >> 4) << 2) + r;
            size_t rb = base + (size_t)rowg * E_;
            #pragma unroll
            for (int fd = 0; fd < 4; ++fd) {
                int d = fd * 16 + (l & 15);
                float ny = (acc[fn][fd][r] - mean) * rinv;
                float rn = ny * gsv[fd] + gbv[fd];
                float g = bf2f(G[rb + d]);
                T[rb + d] = f2bf(g * rn / (1.f + __expf(-g)));
            }
        }
    }
}

// ---------------------------------------------------------------------------
// out = rmsnorm((Xf or Xb) + Y) * scale. Optional f32/bf16 outputs.
__global__ __launch_bounds__(512) void rmsnorm_res(const float* __restrict__ Xf,
                                                   const u16* __restrict__ Xb,
                                                   const float* __restrict__ Y,
                                                   const float* __restrict__ sc,
                                                   float* __restrict__ outf,
                                                   u16* __restrict__ outb) {
    __shared__ float part[8];
    size_t row = blockIdx.x;
    int t = threadIdx.x;
    float xv = Xf ? Xf[row * E_ + t] : bf2f(Xb[row * E_ + t]);
    float v = xv + Y[row * E_ + t];
    float sq = v * v;
    #pragma unroll
    for (int off = 1; off < 64; off <<= 1) sq += __shfl_xor(sq, off, 64);
    if ((t & 63) == 0) part[t >> 6] = sq;
    __syncthreads();
    float tot = 0.0f;
    #pragma unroll
    for (int i = 0; i < 8; ++i) tot += part[i];
    float r = rsqrtf(tot * (1.0f / 512.0f) + 1e-6f);
    float o = v * r * sc[t];
    if (outf) outf[row * E_ + t] = o;
    if (outb) outb[row * E_ + t] = f2bf(o);
}

// ---------------------------------------------------------------------------
extern "C" void kernel_launch(void* const* d_in, const int* in_sizes, int n_in,
                              void* d_out, int out_size, void* d_ws, size_t ws_size,
                              hipStream_t stream) {
    const float* x    = (const float*)d_in[0];
    const float* obs  = (const float*)d_in[1];
    const float* wq1  = (const float*)d_in[2];
    const float* wk1  = (const float*)d_in[3];
    const float* wv1  = (const float*)d_in[4];
    const float* wg1  = (const float*)d_in[5];
    const float* wo1  = (const float*)d_in[6];
    const float* gs1  = (const float*)d_in[7];
    const float* gb1  = (const float*)d_in[8];
    const float* wq2  = (const float*)d_in[9];
    const float* wk2  = (const float*)d_in[10];
    const float* wv2  = (const float*)d_in[11];
    const float* wg2  = (const float*)d_in[12];
    const float* wo2  = (const float*)d_in[13];
    const float* gs2  = (const float*)d_in[14];
    const float* gb2  = (const float*)d_in[15];
    const float* ln1s = (const float*)d_in[16];
    const float* ln2s = (const float*)d_in[17];
    const float* ln3s = (const float*)d_in[18];
    const float* wlin = (const float*)d_in[19];
    const float* wgat = (const float*)d_in[20];
    const float* wout = (const float*)d_in[21];

    u16* wsb = (u16*)d_ws;
    u16* WC1  = wsb;
    u16* WC2  = WC1 + 2048 * 512;
    u16* WF   = WC2 + 2048 * 512;
    u16* WO1t = WF + 1024 * 512;
    u16* WO2t = WO1t + 512 * 512;
    u16* WOUt = WO2t + 512 * 512;
    u16* XB   = WOUt + 512 * 512;
    u16* OB   = XB + NTOT;
    u16* QB   = OB + NTOT;
    u16* KB   = QB + NTOT;
    u16* VT   = KB + NTOT;
    u16* GB   = VT + NTOT;
    u16* TB   = GB + NTOT;
    float* GF = (float*)QB;   // f32 WO-output, aliases QB+KB (free at that point)

    dim3 tG(256);

    prep_weights<<<dim3(8, 104), tG, 0, stream>>>(wq1, wk1, wv1, wg1, wq2, wk2, wv2, wg2,
                                                  wgat, wlin, wo1, wo2, wout,
                                                  WC1, WC2, WF, WO1t, WO2t, WOUt);
    cvt_both<<<NTOT / 1024, tG, 0, stream>>>(x, obs, XB, OB);

    // ---- stage 1: x1 = rmsnorm(x + msr(x,x,x))
    gemm_qkvg<<<1024, tG, 0, stream>>>(XB, XB, WC1, QB, KB, VT, GB);
    retention_fused<<<512, tG, 0, stream>>>(QB, KB, VT, GB, gs1, gb1, TB);
    gemm_wo<<<512, tG, 0, stream>>>(TB, WO1t, GF);
    rmsnorm_res<<<M_, 512, 0, stream>>>(x, nullptr, GF, ln1s, nullptr, XB);

    // ---- stage 2: x2 = rmsnorm(obs + msr(key=x1, query=obs, value=x1))
    gemm_qkvg<<<1024, tG, 0, stream>>>(OB, XB, WC2, QB, KB, VT, GB);
    retention_fused<<<512, tG, 0, stream>>>(QB, KB, VT, GB, gs2, gb2, TB);
    gemm_wo<<<512, tG, 0, stream>>>(TB, WO2t, GF);
    rmsnorm_res<<<M_, 512, 0, stream>>>(obs, nullptr, GF, ln2s, nullptr, OB);  // x2 -> OB (bf16)

    // ---- FFN: out = rmsnorm(x2 + (swish(x2@Wg)*(x2@Wl))@Wo)
    gemm_ffn<<<1024, tG, 0, stream>>>(OB, WF, TB);
    gemm_wo<<<512, tG, 0, stream>>>(TB, WOUt, GF);
    rmsnorm_res<<<M_, 512, 0, stream>>>(nullptr, OB, GF, ln3s, (float*)d_out, nullptr);
}

// Round 6
// 203.615 us; speedup vs baseline: 9.9233x; 1.0357x over previous
//
#include <hip/hip_runtime.h>
#include <hip/hip_bf16.h>
#include <stdint.h>

typedef unsigned short u16;
typedef unsigned int   u32;
typedef __bf16 bf16x8 __attribute__((ext_vector_type(8)));
typedef u16    u16x8  __attribute__((ext_vector_type(8)));
typedef float  f32x4  __attribute__((ext_vector_type(4)));

#define E_   512
#define H_   8
#define DH_  64
#define B_   8
#define S_   1024
#define M_   (B_ * S_)
#define NTOT (M_ * E_)

__device__ __forceinline__ u16 f2bf(float f) {
    u32 x = __float_as_uint(f);
    x += 0x7fffu + ((x >> 16) & 1u);
    return (u16)(x >> 16);
}
__device__ __forceinline__ float bf2f(u16 b) { return __uint_as_float((u32)b << 16); }
__device__ __forceinline__ bf16x8 as_bf(u16x8 v) {
    union { u16x8 u; bf16x8 b; } x; x.u = v; return x.b;
}
__device__ __forceinline__ u32 cvtpk(float lo, float hi) {
    u32 r;
    asm("v_cvt_pk_bf16_f32 %0, %1, %2" : "=v"(r) : "v"(lo), "v"(hi));
    return r;
}
__device__ __forceinline__ void gll16(const u16* g, u16* l) {
    __builtin_amdgcn_global_load_lds((const __attribute__((address_space(1))) u32*)g,
                                     (__attribute__((address_space(3))) u32*)l, 16, 0, 0);
}
__device__ __forceinline__ void xcd_map(int f, int nwg, int gx, int& bx, int& by) {
    int nf = (f & 7) * (nwg >> 3) + (f >> 3);
    bx = nf % gx; by = nf / gx;
}

// ---------------------------------------------------------------------------
__global__ __launch_bounds__(256) void prep_weights(
    const float* __restrict__ wq1, const float* __restrict__ wk1, const float* __restrict__ wv1,
    const float* __restrict__ wg1, const float* __restrict__ wq2, const float* __restrict__ wk2,
    const float* __restrict__ wv2, const float* __restrict__ wg2, const float* __restrict__ wgat,
    const float* __restrict__ wlin, const float* __restrict__ wo1, const float* __restrict__ wo2,
    const float* __restrict__ wout,
    u16* __restrict__ WC1, u16* __restrict__ WC2, u16* __restrict__ WF,
    u16* __restrict__ WO1t, u16* __restrict__ WO2t, u16* __restrict__ WOUt) {
    __shared__ float tle[64][65];
    const int rt = blockIdx.y, c0 = blockIdx.x * 64, tid = threadIdx.x;
    u16* dst; const float* src; int lr0; bool qkv = false; int nb0 = 0, h = 0;
    if (rt < 64) {
        bool s1 = rt < 32;
        dst = s1 ? WC1 : WC2;
        int r = (rt & 31) * 64; lr0 = r;
        if (r < 1536) {
            qkv = true; h = (r >> 6) & 7;
            src = (r < 512) ? (s1 ? wq1 : wq2) : (r < 1024) ? (s1 ? wk1 : wk2) : (s1 ? wv1 : wv2);
        } else { src = s1 ? wg1 : wg2; nb0 = r - 1536; }
    } else if (rt < 80) {
        dst = WF; int r = (rt - 64) * 64; lr0 = r;
        src = (r < 512) ? wgat : wlin; nb0 = r & 511;
    } else if (rt < 88) { dst = WO1t; lr0 = (rt - 80) * 64; src = wo1; nb0 = lr0; }
    else if (rt < 96)   { dst = WO2t; lr0 = (rt - 88) * 64; src = wo2; nb0 = lr0; }
    else                { dst = WOUt; lr0 = (rt - 96) * 64; src = wout; nb0 = lr0; }

    #pragma unroll
    for (int i = 0; i < 16; ++i) {
        int idx = i * 256 + tid, a = idx >> 6, b = idx & 63;
        tle[a][b] = qkv ? src[(size_t)(h * 512 + c0 + a) * 64 + b]
                        : src[(size_t)(c0 + a) * 512 + nb0 + b];
    }
    __syncthreads();
    #pragma unroll
    for (int i = 0; i < 16; ++i) {
        int idx = i * 256 + tid;
        dst[(size_t)(lr0 + (idx >> 6)) * 512 + c0 + (idx & 63)] = f2bf(tle[idx & 63][idx >> 6]);
    }
}

// ---------------------------------------------------------------------------
__global__ __launch_bounds__(256) void cvt_both(const float* __restrict__ x,
                                                const float* __restrict__ obs,
                                                u16* __restrict__ XB, u16* __restrict__ OB) {
    int i = blockIdx.x * 256 + threadIdx.x;
    float4 v = ((const float4*)x)[i];
    ushort4 o;
    o.x = f2bf(v.x); o.y = f2bf(v.y); o.z = f2bf(v.z); o.w = f2bf(v.w);
    ((ushort4*)XB)[i] = o;
    v = ((const float4*)obs)[i];
    o.x = f2bf(v.x); o.y = f2bf(v.y); o.z = f2bf(v.z); o.w = f2bf(v.w);
    ((ushort4*)OB)[i] = o;
}

// ---------------------------------------------------------------------------
// Fused Q/K/V/G projection GEMM. K also written transposed (KT[bh][dk][s]),
// V written transposed (VT[bh][dv][s]). Single-buffer LDS, m97 structure.
__global__ __launch_bounds__(256) void gemm_qkvg(const u16* __restrict__ A1,
                                                 const u16* __restrict__ A2,
                                                 const u16* __restrict__ W,
                                                 u16* __restrict__ QB, u16* __restrict__ KB,
                                                 u16* __restrict__ KT, u16* __restrict__ VT,
                                                 u16* __restrict__ GB) {
    __shared__ u16 Als[128 * 64];
    __shared__ u16 Bls[128 * 64];
    const int tid = threadIdx.x;
    const int l = tid & 63, w = tid >> 6;
    const int wm = w & 1, wn = w >> 1;
    int bx, by; xcd_map(blockIdx.x, 1024, 16, bx, by);
    const int bm = by * 128, bn = bx * 128;
    const int which = bx >> 2;
    const u16* A = (which == 1 || which == 2) ? A2 : A1;

    size_t srcA[4], srcB[4]; int ldst[4];
    #pragma unroll
    for (int c = 0; c < 4; ++c) {
        int row = c * 32 + w * 8 + (l >> 3);
        int chs = (l & 7) ^ (row & 7);
        srcA[c] = (size_t)(bm + row) * E_ + chs * 8;
        srcB[c] = (size_t)(bn + row) * E_ + chs * 8;
        ldst[c] = c * 2048 + w * 512;
    }
    int aoff[2][4], boff[2][4];
    #pragma unroll
    for (int kk = 0; kk < 2; ++kk)
        #pragma unroll
        for (int f = 0; f < 4; ++f) {
            int ra = wm * 64 + f * 16 + (l & 15);
            int rb = wn * 64 + f * 16 + (l & 15);
            int ch = kk * 4 + (l >> 4);
            aoff[kk][f] = ra * 128 + ((ch ^ (ra & 7)) << 4);
            boff[kk][f] = rb * 128 + ((ch ^ (rb & 7)) << 4);
        }

    f32x4 acc[4][4] = {};
    for (int t = 0; t < 8; ++t) {
        const int k1 = t * 64;
        #pragma unroll
        for (int c = 0; c < 4; ++c) {
            gll16(A + srcA[c] + k1, &Als[ldst[c]]);
            gll16(W + srcB[c] + k1, &Bls[ldst[c]]);
        }
        __syncthreads();
        #pragma unroll
        for (int kk = 0; kk < 2; ++kk) {
            bf16x8 af[4], bfr[4];
            #pragma unroll
            for (int f = 0; f < 4; ++f) {
                af[f]  = as_bf(*(const u16x8*)((const char*)Als + aoff[kk][f]));
                bfr[f] = as_bf(*(const u16x8*)((const char*)Bls + boff[kk][f]));
            }
            #pragma unroll
            for (int m = 0; m < 4; ++m)
                #pragma unroll
                for (int n = 0; n < 4; ++n)
                    acc[m][n] = __builtin_amdgcn_mfma_f32_16x16x32_bf16(af[m], bfr[n], acc[m][n], 0, 0, 0);
        }
        __syncthreads();
    }

    #pragma unroll
    for (int m = 0; m < 4; ++m) {
        int row = bm + wm * 64 + m * 16 + ((l >> 4) << 2);
        #pragma unroll
        for (int n = 0; n < 4; ++n) {
            int coll = (bn & 511) + wn * 64 + n * 16 + (l & 15);
            f32x4 v = acc[m][n];
            size_t va = (((size_t)(row >> 10) * 8 + (coll >> 6)) * 64 + (coll & 63)) * 1024
                        + (row & 1023);
            if (which == 2) {
                ushort4 o;
                o.x = f2bf(v[0]); o.y = f2bf(v[1]); o.z = f2bf(v[2]); o.w = f2bf(v[3]);
                *(ushort4*)(VT + va) = o;
            } else if (which == 1) {
                #pragma unroll
                for (int r = 0; r < 4; ++r) KB[(size_t)(row + r) * E_ + coll] = f2bf(v[r]);
                ushort4 o;
                o.x = f2bf(v[0]); o.y = f2bf(v[1]); o.z = f2bf(v[2]); o.w = f2bf(v[3]);
                *(ushort4*)(KT + va) = o;
            } else {
                u16* dst = (which == 0) ? QB : GB;
                #pragma unroll
                for (int r = 0; r < 4; ++r) dst[(size_t)(row + r) * E_ + coll] = f2bf(v[r]);
            }
        }
    }
}

// ---------------------------------------------------------------------------
// Per-chunk decayed state: U^T[bh][c][dv][dk] = sum_m k^(127-m) V[m][dv] K[m][dk]
// Computed as VT @ (wK) with fragments loaded directly from global (no LDS).
__global__ __launch_bounds__(256) void state_u(const u16* __restrict__ KT,
                                               const u16* __restrict__ VT,
                                               u16* __restrict__ U) {
    const int id = blockIdx.x;            // 512 = bh*8 + c
    const int bh = id >> 3, c = id & 7;
    const int h = bh & 7;
    const int l = threadIdx.x & 63, w = threadIdx.x >> 6;
    const float kappa = 1.0f - __expf(-3.46573590f + (float)h * -0.39608410f);
    const float log2k = log2f(kappa);
    const float ik = 1.0f / kappa;

    // A-frags from VT: i = dv = w*16 + (l&15), k = m
    bf16x8 af[4];
    {
        size_t vbase = ((size_t)bh * 64 + (w * 16 + (l & 15))) * 1024 + c * 128 + ((l >> 4) << 3);
        #pragma unroll
        for (int kk = 0; kk < 4; ++kk)
            af[kk] = as_bf(*(const u16x8*)(VT + vbase + kk * 32));
    }

    f32x4 acc[4] = {};
    #pragma unroll
    for (int fd = 0; fd < 4; ++fd) {
        size_t kbase = ((size_t)bh * 64 + (fd * 16 + (l & 15))) * 1024 + c * 128 + ((l >> 4) << 3);
        #pragma unroll
        for (int kk = 0; kk < 4; ++kk) {
            u16x8 kv = *(const u16x8*)(KT + kbase + kk * 32);
            int mb = kk * 32 + ((l >> 4) << 3);
            float wj = exp2f((float)(127 - mb) * log2k);
            u16x8 kw;
            #pragma unroll
            for (int j = 0; j < 8; ++j) { kw[j] = f2bf(bf2f(kv[j]) * wj); wj *= ik; }
            acc[fd] = __builtin_amdgcn_mfma_f32_16x16x32_bf16(af[kk], as_bf(kw), acc[fd], 0, 0, 0);
        }
    }

    #pragma unroll
    for (int fd = 0; fd < 4; ++fd) {
        int dv = w * 16 + ((l >> 4) << 2);
        int dk = fd * 16 + (l & 15);
        size_t ub = ((size_t)id * 64 + dv) * 64 + dk;
        #pragma unroll
        for (int r = 0; r < 4; ++r) U[ub + (size_t)r * 64] = f2bf(acc[fd][r]);
    }
}

// ---------------------------------------------------------------------------
// Chunked retention + GroupNorm + swish gate. One block per (bh, chunk).
// O = kappa^(nl+1) * Q @ S_c  +  intra-chunk causal retention.
__global__ __launch_bounds__(256) void retention_chunk(
        const u16* __restrict__ Q, const u16* __restrict__ K,
        const u16* __restrict__ VT, const u16* __restrict__ U,
        const u16* __restrict__ G,
        const float* __restrict__ gs, const float* __restrict__ gb,
        u16* __restrict__ T) {
    __shared__ u16 Ks[128 * 64], Vts[64 * 128], Ps[128 * 64], Ss[64 * 64];
    const int tid = threadIdx.x;
    const int l = tid & 63, w = tid >> 6;
    const int id = blockIdx.x;
    const int bh = id >> 3, c = id & 7;
    const int h = bh & 7;
    const int n0 = c * 128;
    const size_t base = (size_t)(bh >> 3) * (S_ * E_) + h * DH_;

    const float kappa = 1.0f - __expf(-3.46573590f + (float)h * -0.39608410f);
    const float log2k = log2f(kappa);
    const float ik = 1.0f / kappa;
    const float ikp2 = ik * ik, ikp3 = ikp2 * ik;

    float gsv[4], gbv[4];
    #pragma unroll
    for (int fd = 0; fd < 4; ++fd) {
        gsv[fd] = gs[h * 64 + fd * 16 + (l & 15)];
        gbv[fd] = gb[h * 64 + fd * 16 + (l & 15)];
    }

    // stage K rows + VT cols of this chunk
    #pragma unroll
    for (int cc = 0; cc < 4; ++cc) {
        int row = cc * 32 + w * 8 + (l >> 3);
        int chs = (l & 7) ^ (row & 7);
        gll16(K + base + (size_t)(n0 + row) * E_ + chs * 8, &Ks[cc * 2048 + w * 512]);
        int d = cc * 16 + w * 4 + (l >> 4);
        int vch = (l & 15) ^ (d & 15);
        gll16(VT + ((size_t)bh * 64 + d) * 1024 + n0 + vch * 8, &Vts[cc * 2048 + w * 512]);
    }

    // Q fragments direct from global (per-wave rows, no sharing)
    bf16x8 qf[2][2];
    #pragma unroll
    for (int kk = 0; kk < 2; ++kk)
        #pragma unroll
        for (int fn = 0; fn < 2; ++fn) {
            int n = n0 + fn * 64 + w * 16 + (l & 15);
            qf[kk][fn] = as_bf(*(const u16x8*)(Q + base + (size_t)n * E_ + kk * 32 + ((l >> 4) << 3)));
        }

    // S^T = sum_{c'<c} kappa^(128(c-1-c')) U^T_{c'}  (f32 accum -> bf16 LDS)
    if (c > 0) {
        float accs[16];
        #pragma unroll
        for (int j = 0; j < 16; ++j) accs[j] = 0.f;
        const float kC = exp2f(128.0f * log2k);
        float wc = 1.0f;
        size_t ub = (size_t)bh * (8 * 4096) + tid * 16;
        for (int cp = c - 1; cp >= 0; --cp) {
            const u16* up = U + ub + (size_t)cp * 4096;
            u16x8 a = *(const u16x8*)up;
            u16x8 b = *(const u16x8*)(up + 8);
            #pragma unroll
            for (int j = 0; j < 8; ++j) {
                accs[j]     += bf2f(a[j]) * wc;
                accs[8 + j] += bf2f(b[j]) * wc;
            }
            wc *= kC;
        }
        int dv = tid >> 2, ch0 = (tid & 3) << 1;
        #pragma unroll
        for (int hh = 0; hh < 2; ++hh) {
            uint4 pk;
            pk.x = cvtpk(accs[hh * 8 + 0], accs[hh * 8 + 1]);
            pk.y = cvtpk(accs[hh * 8 + 2], accs[hh * 8 + 3]);
            pk.z = cvtpk(accs[hh * 8 + 4], accs[hh * 8 + 5]);
            pk.w = cvtpk(accs[hh * 8 + 6], accs[hh * 8 + 7]);
            *(uint4*)((char*)Ss + dv * 128 + (((ch0 + hh) ^ (dv & 7)) << 4)) = pk;
        }
    }
    __syncthreads();

    f32x4 acc[2][4] = {};

    // ---- inter-chunk: acc = (Q @ S) then scale rows by kappa^(nl+1)
    if (c > 0) {
        __builtin_amdgcn_s_setprio(1);
        #pragma unroll
        for (int kk = 0; kk < 2; ++kk) {
            bf16x8 sf[4];
            #pragma unroll
            for (int fd = 0; fd < 4; ++fd) {
                int dv = fd * 16 + (l & 15);
                int ch = kk * 4 + (l >> 4);
                sf[fd] = as_bf(*(const u16x8*)((const char*)Ss + dv * 128 + ((ch ^ (dv & 7)) << 4)));
            }
            #pragma unroll
            for (int fn = 0; fn < 2; ++fn)
                #pragma unroll
                for (int fd = 0; fd < 4; ++fd)
                    acc[fn][fd] = __builtin_amdgcn_mfma_f32_16x16x32_bf16(qf[kk][fn], sf[fd], acc[fn][fd], 0, 0, 0);
        }
        __builtin_amdgcn_s_setprio(0);
        #pragma unroll
        for (int fn = 0; fn < 2; ++fn) {
            int nl0 = fn * 64 + w * 16 + ((l >> 4) << 2);
            float fr0 = exp2f((float)(nl0 + 1) * log2k);
            float fr1 = fr0 * kappa, fr2 = fr1 * kappa, fr3 = fr2 * kappa;
            #pragma unroll
            for (int fd = 0; fd < 4; ++fd) {
                acc[fn][fd][0] *= fr0; acc[fn][fd][1] *= fr1;
                acc[fn][fd][2] *= fr2; acc[fn][fd][3] *= fr3;
            }
        }
    }

    // ---- intra: mh0 -> {fn0 masked, fn1 fast}; mh1 -> {fn1 masked}
    #pragma unroll
    for (int mh = 0; mh < 2; ++mh) {
        const int m0l = mh * 64;
        bf16x8 kf[2][4];
        #pragma unroll
        for (int kk = 0; kk < 2; ++kk)
            #pragma unroll
            for (int f = 0; f < 4; ++f) {
                int row = m0l + f * 16 + (l & 15);
                int ch = kk * 4 + (l >> 4);
                kf[kk][f] = as_bf(*(const u16x8*)((const char*)Ks + row * 128 + ((ch ^ (row & 7)) << 4)));
            }
        #pragma unroll
        for (int fn = 0; fn < 2; ++fn) {
            if (mh == 1 && fn == 0) continue;
            f32x4 s[4] = {};
            __builtin_amdgcn_s_setprio(1);
            #pragma unroll
            for (int kk = 0; kk < 2; ++kk)
                #pragma unroll
                for (int f = 0; f < 4; ++f)
                    s[f] = __builtin_amdgcn_mfma_f32_16x16x32_bf16(kf[kk][f], qf[kk][fn], s[f], 0, 0, 0);
            __builtin_amdgcn_s_setprio(0);
            const bool fast = (mh == 0 && fn == 1);
            int nl = fn * 64 + w * 16 + (l & 15);
            #pragma unroll
            for (int f = 0; f < 4; ++f) {
                int mbl = m0l + f * 16 + ((l >> 4) << 2);
                int delta = nl - mbl;
                float wb = exp2f((float)delta * log2k);
                f32x4 v = s[f];
                float p0, p1, p2, p3;
                if (fast) {
                    float w1 = wb * ik, w2 = w1 * ik, w3 = w2 * ik;
                    p0 = v[0] * wb; p1 = v[1] * w1; p2 = v[2] * w2; p3 = v[3] * w3;
                } else {
                    p0 = (delta >= 0) ? v[0] * wb : 0.f;
                    p1 = (delta >= 1) ? v[1] * wb * ik : 0.f;
                    p2 = (delta >= 2) ? v[2] * wb * ikp2 : 0.f;
                    p3 = (delta >= 3) ? v[3] * wb * ikp3 : 0.f;
                }
                int mcl = f * 16 + ((l >> 4) << 2);
                int byteoff = nl * 128 + (((mcl >> 3) ^ (nl & 7)) << 4) + ((mcl & 4) << 1);
                uint2 pk;
                pk.x = cvtpk(p0, p1);
                pk.y = cvtpk(p2, p3);
                *(uint2*)((char*)Ps + byteoff) = pk;
            }
        }
        // PV for this m-half
        #pragma unroll
        for (int km = 0; km < 2; ++km) {
            bf16x8 pf[2];
            #pragma unroll
            for (int fn = 0; fn < 2; ++fn) {
                if (mh == 1 && fn == 0) continue;
                int row = fn * 64 + w * 16 + (l & 15);
                int ch = km * 4 + (l >> 4);
                pf[fn] = as_bf(*(const u16x8*)((const char*)Ps + row * 128 + ((ch ^ (row & 7)) << 4)));
            }
            __builtin_amdgcn_s_setprio(1);
            #pragma unroll
            for (int fd = 0; fd < 4; ++fd) {
                int d = fd * 16 + (l & 15);
                int mch = mh * 8 + km * 4 + (l >> 4);
                bf16x8 vfr = as_bf(*(const u16x8*)((const char*)Vts + d * 256 + ((mch ^ (d & 15)) << 4)));
                #pragma unroll
                for (int fn = 0; fn < 2; ++fn) {
                    if (mh == 1 && fn == 0) continue;
                    acc[fn][fd] = __builtin_amdgcn_mfma_f32_16x16x32_bf16(pf[fn], vfr, acc[fn][fd], 0, 0, 0);
                }
            }
            __builtin_amdgcn_s_setprio(0);
        }
    }

    // ---- fused GroupNorm + swish gate
    #pragma unroll
    for (int fn = 0; fn < 2; ++fn) {
        #pragma unroll
        for (int r = 0; r < 4; ++r) {
            float s1 = 0.f, s2 = 0.f;
            #pragma unroll
            for (int fd = 0; fd < 4; ++fd) { float v = acc[fn][fd][r]; s1 += v; s2 += v * v; }
            #pragma unroll
            for (int off = 1; off < 16; off <<= 1) {
                s1 += __shfl_xor(s1, off, 64);
                s2 += __shfl_xor(s2, off, 64);
            }
            float mean = s1 * (1.f / 64.f);
            float var  = s2 * (1.f / 64.f) - mean * mean;
            float rinv = rsqrtf(var + 1e-5f);
            int rowg = n0 + fn * 64 + w * 16 + ((l >> 4) << 2) + r;
            size_t rb = base + (size_t)rowg * E_;
            #pragma unroll
            for (int fd = 0; fd < 4; ++fd) {
                int d = fd * 16 + (l & 15);
                float ny = (acc[fn][fd][r] - mean) * rinv;
                float rn = ny * gsv[fd] + gbv[fd];
                float g = bf2f(G[rb + d]);
                T[rb + d] = f2bf(g * rn / (1.f + __expf(-g)));
            }
        }
    }
}

// ---------------------------------------------------------------------------
__global__ __launch_bounds__(256) void gemm_wo(const u16* __restrict__ A,
                                               const u16* __restrict__ W,
                                               float* __restrict__ Cf) {
    __shared__ u16 Als[64 * 64];
    __shared__ u16 Bls[128 * 64];
    const int tid = threadIdx.x;
    const int l = tid & 63, w = tid >> 6;
    const int wm = w & 1, wn = w >> 1;
    int bx, by; xcd_map(blockIdx.x, 512, 4, bx, by);
    const int bm = by * 64, bn = bx * 128;

    size_t srcA[2], srcB[4]; int ldstA[2], ldstB[4];
    #pragma unroll
    for (int c = 0; c < 4; ++c) {
        int row = c * 32 + w * 8 + (l >> 3);
        int chs = (l & 7) ^ (row & 7);
        if (c < 2) { srcA[c] = (size_t)(bm + row) * E_ + chs * 8; ldstA[c] = c * 2048 + w * 512; }
        srcB[c] = (size_t)(bn + row) * E_ + chs * 8;
        ldstB[c] = c * 2048 + w * 512;
    }
    int aoff[2][2], boff[2][4];
    #pragma unroll
    for (int kk = 0; kk < 2; ++kk) {
        #pragma unroll
        for (int f = 0; f < 2; ++f) {
            int ra = wm * 32 + f * 16 + (l & 15);
            aoff[kk][f] = ra * 128 + (((kk * 4 + (l >> 4)) ^ (ra & 7)) << 4);
        }
        #pragma unroll
        for (int f = 0; f < 4; ++f) {
            int rb = wn * 64 + f * 16 + (l & 15);
            boff[kk][f] = rb * 128 + (((kk * 4 + (l >> 4)) ^ (rb & 7)) << 4);
        }
    }

    f32x4 acc[2][4] = {};
    for (int t = 0; t < 8; ++t) {
        const int k1 = t * 64;
        #pragma unroll
        for (int c = 0; c < 2; ++c) gll16(A + srcA[c] + k1, &Als[ldstA[c]]);
        #pragma unroll
        for (int c = 0; c < 4; ++c) gll16(W + srcB[c] + k1, &Bls[ldstB[c]]);
        __syncthreads();
        #pragma unroll
        for (int kk = 0; kk < 2; ++kk) {
            bf16x8 af[2], bfr[4];
            #pragma unroll
            for (int f = 0; f < 2; ++f) af[f] = as_bf(*(const u16x8*)((const char*)Als + aoff[kk][f]));
            #pragma unroll
            for (int f = 0; f < 4; ++f) bfr[f] = as_bf(*(const u16x8*)((const char*)Bls + boff[kk][f]));
            #pragma unroll
            for (int m = 0; m < 2; ++m)
                #pragma unroll
                for (int n = 0; n < 4; ++n)
                    acc[m][n] = __builtin_amdgcn_mfma_f32_16x16x32_bf16(af[m], bfr[n], acc[m][n], 0, 0, 0);
        }
        __syncthreads();
    }

    #pragma unroll
    for (int m = 0; m < 2; ++m) {
        int row = bm + wm * 32 + m * 16 + ((l >> 4) << 2);
        #pragma unroll
        for (int n = 0; n < 4; ++n) {
            int col = bn + wn * 64 + n * 16 + (l & 15);
            f32x4 v = acc[m][n];
            #pragma unroll
            for (int r = 0; r < 4; ++r) Cf[(size_t)(row + r) * E_ + col] = v[r];
        }
    }
}

// ---------------------------------------------------------------------------
__global__ __launch_bounds__(256) void gemm_ffn(const u16* __restrict__ A,
                                                const u16* __restrict__ W,
                                                u16* __restrict__ T) {
    __shared__ u16 Als[64 * 64];
    __shared__ u16 Bgs[64 * 64];
    __shared__ u16 Bls[64 * 64];
    const int tid = threadIdx.x;
    const int l = tid & 63, w = tid >> 6;
    const int wm = w & 1, wn = w >> 1;
    int bx, by; xcd_map(blockIdx.x, 1024, 8, bx, by);
    const int bm = by * 64, bn = bx * 64;

    size_t srcA[2], srcG[2], srcL[2]; int ldst[2];
    #pragma unroll
    for (int c = 0; c < 2; ++c) {
        int row = c * 32 + w * 8 + (l >> 3);
        int chs = (l & 7) ^ (row & 7);
        srcA[c] = (size_t)(bm + row) * E_ + chs * 8;
        srcG[c] = (size_t)(bn + row) * E_ + chs * 8;
        srcL[c] = (size_t)(512 + bn + row) * E_ + chs * 8;
        ldst[c] = c * 2048 + w * 512;
    }
    int aoff[2][2], goff[2][2];
    #pragma unroll
    for (int kk = 0; kk < 2; ++kk)
        #pragma unroll
        for (int f = 0; f < 2; ++f) {
            int ra = wm * 32 + f * 16 + (l & 15);
            int rb = wn * 32 + f * 16 + (l & 15);
            aoff[kk][f] = ra * 128 + (((kk * 4 + (l >> 4)) ^ (ra & 7)) << 4);
            goff[kk][f] = rb * 128 + (((kk * 4 + (l >> 4)) ^ (rb & 7)) << 4);
        }

    f32x4 accg[2][2] = {}, accl[2][2] = {};
    for (int t = 0; t < 8; ++t) {
        const int k1 = t * 64;
        #pragma unroll
        for (int c = 0; c < 2; ++c) {
            gll16(A + srcA[c] + k1, &Als[ldst[c]]);
            gll16(W + srcG[c] + k1, &Bgs[ldst[c]]);
            gll16(W + srcL[c] + k1, &Bls[ldst[c]]);
        }
        __syncthreads();
        #pragma unroll
        for (int kk = 0; kk < 2; ++kk) {
            bf16x8 af[2], bg[2], bl[2];
            #pragma unroll
            for (int f = 0; f < 2; ++f) {
                af[f] = as_bf(*(const u16x8*)((const char*)Als + aoff[kk][f]));
                bg[f] = as_bf(*(const u16x8*)((const char*)Bgs + goff[kk][f]));
                bl[f] = as_bf(*(const u16x8*)((const char*)Bls + goff[kk][f]));
            }
            #pragma unroll
            for (int m = 0; m < 2; ++m)
                #pragma unroll
                for (int n = 0; n < 2; ++n) {
                    accg[m][n] = __builtin_amdgcn_mfma_f32_16x16x32_bf16(af[m], bg[n], accg[m][n], 0, 0, 0);
                    accl[m][n] = __builtin_amdgcn_mfma_f32_16x16x32_bf16(af[m], bl[n], accl[m][n], 0, 0, 0);
                }
        }
        __syncthreads();
    }

    #pragma unroll
    for (int m = 0; m < 2; ++m) {
        int row = bm + wm * 32 + m * 16 + ((l >> 4) << 2);
        #pragma unroll
        for (int n = 0; n < 2; ++n) {
            int col = bn + wn * 32 + n * 16 + (l & 15);
            #pragma unroll
            for (int r = 0; r < 4; ++r) {
                float g = accg[m][n][r], lv = accl[m][n][r];
                T[(size_t)(row + r) * E_ + col] = f2bf(g * lv / (1.f + __expf(-g)));
            }
        }
    }
}

// ---------------------------------------------------------------------------
__global__ __launch_bounds__(512) void rmsnorm_res(const float* __restrict__ Xf,
                                                   const u16* __restrict__ Xb,
                                                   const float* __restrict__ Y,
                                                   const float* __restrict__ sc,
                                                   float* __restrict__ outf,
                                                   u16* __restrict__ outb) {
    __shared__ float part[8];
    size_t row = blockIdx.x;
    int t = threadIdx.x;
    float xv = Xf ? Xf[row * E_ + t] : bf2f(Xb[row * E_ + t]);
    float v = xv + Y[row * E_ + t];
    float sq = v * v;
    #pragma unroll
    for (int off = 1; off < 64; off <<= 1) sq += __shfl_xor(sq, off, 64);
    if ((t & 63) == 0) part[t >> 6] = sq;
    __syncthreads();
    float tot = 0.0f;
    #pragma unroll
    for (int i = 0; i < 8; ++i) tot += part[i];
    float r = rsqrtf(tot * (1.0f / 512.0f) + 1e-6f);
    float o = v * r * sc[t];
    if (outf) outf[row * E_ + t] = o;
    if (outb) outb[row * E_ + t] = f2bf(o);
}

// ---------------------------------------------------------------------------
extern "C" void kernel_launch(void* const* d_in, const int* in_sizes, int n_in,
                              void* d_out, int out_size, void* d_ws, size_t ws_size,
                              hipStream_t stream) {
    const float* x    = (const float*)d_in[0];
    const float* obs  = (const float*)d_in[1];
    const float* wq1  = (const float*)d_in[2];
    const float* wk1  = (const float*)d_in[3];
    const float* wv1  = (const float*)d_in[4];
    const float* wg1  = (const float*)d_in[5];
    const float* wo1  = (const float*)d_in[6];
    const float* gs1  = (const float*)d_in[7];
    const float* gb1  = (const float*)d_in[8];
    const float* wq2  = (const float*)d_in[9];
    const float* wk2  = (const float*)d_in[10];
    const float* wv2  = (const float*)d_in[11];
    const float* wg2  = (const float*)d_in[12];
    const float* wo2  = (const float*)d_in[13];
    const float* gs2  = (const float*)d_in[14];
    const float* gb2  = (const float*)d_in[15];
    const float* ln1s = (const float*)d_in[16];
    const float* ln2s = (const float*)d_in[17];
    const float* ln3s = (const float*)d_in[18];
    const float* wlin = (const float*)d_in[19];
    const float* wgat = (const float*)d_in[20];
    const float* wout = (const float*)d_in[21];

    u16* wsb = (u16*)d_ws;
    u16* WC1  = wsb;
    u16* WC2  = WC1 + 2048 * 512;
    u16* WF   = WC2 + 2048 * 512;
    u16* WO1t = WF + 1024 * 512;
    u16* WO2t = WO1t + 512 * 512;
    u16* WOUt = WO2t + 512 * 512;
    u16* XB   = WOUt + 512 * 512;
    u16* OB   = XB + NTOT;
    u16* QB   = OB + NTOT;
    u16* KB   = QB + NTOT;
    u16* KT   = KB + NTOT;
    u16* VT   = KT + NTOT;
    u16* GB   = VT + NTOT;
    u16* TB   = GB + NTOT;
    u16* UB   = TB + NTOT;                    // 64*8*64*64 = 2.1M elems
    float* GF = (float*)QB;                   // f32 WO-output, aliases QB+KB

    dim3 tG(256);

    prep_weights<<<dim3(8, 104), tG, 0, stream>>>(wq1, wk1, wv1, wg1, wq2, wk2, wv2, wg2,
                                                  wgat, wlin, wo1, wo2, wout,
                                                  WC1, WC2, WF, WO1t, WO2t, WOUt);
    cvt_both<<<NTOT / 1024, tG, 0, stream>>>(x, obs, XB, OB);

    // ---- stage 1: x1 = rmsnorm(x + msr(x,x,x))
    gemm_qkvg<<<1024, tG, 0, stream>>>(XB, XB, WC1, QB, KB, KT, VT, GB);
    state_u<<<512, tG, 0, stream>>>(KT, VT, UB);
    retention_chunk<<<512, tG, 0, stream>>>(QB, KB, VT, UB, GB, gs1, gb1, TB);
    gemm_wo<<<512, tG, 0, stream>>>(TB, WO1t, GF);
    rmsnorm_res<<<M_, 512, 0, stream>>>(x, nullptr, GF, ln1s, nullptr, XB);

    // ---- stage 2: x2 = rmsnorm(obs + msr(key=x1, query=obs, value=x1))
    gemm_qkvg<<<1024, tG, 0, stream>>>(OB, XB, WC2, QB, KB, KT, VT, GB);
    state_u<<<512, tG, 0, stream>>>(KT, VT, UB);
    retention_chunk<<<512, tG, 0, stream>>>(QB, KB, VT, UB, GB, gs2, gb2, TB);
    gemm_wo<<<512, tG, 0, stream>>>(TB, WO2t, GF);
    rmsnorm_res<<<M_, 512, 0, stream>>>(obs, nullptr, GF, ln2s, nullptr, OB);  // x2 -> OB

    // ---- FFN: out = rmsnorm(x2 + (swish(x2@Wg)*(x2@Wl))@Wo)
    gemm_ffn<<<1024, tG, 0, stream>>>(OB, WF, TB);
    gemm_wo<<<512, tG, 0, stream>>>(TB, WOUt, GF);
    rmsnorm_res<<<M_, 512, 0, stream>>>(nullptr, OB, GF, ln3s, (float*)d_out, nullptr);
}